// Round 6
// baseline (262.739 us; speedup 1.0000x reference)
//
#include <hip/hip_runtime.h>
#include <hip/hip_bf16.h>

#define B_ 4
#define C_ 512
#define L_ 2048
#define H_ 8
#define D_ 64
#define EPS_ 1e-5f

using short8 = __attribute__((ext_vector_type(8))) short;
using s4v    = __attribute__((ext_vector_type(4))) short;
using f32x4  = __attribute__((ext_vector_type(4))) float;
using f32x16 = __attribute__((ext_vector_type(16))) float;
using uint2v = __attribute__((ext_vector_type(2))) unsigned int;

static __device__ __forceinline__ short f2bf(float f) {
  __hip_bfloat16 h = __float2bfloat16(f);
  return __builtin_bit_cast(short, h);
}
static __device__ __forceinline__ float bf2f(short s) {
  return __bfloat162float(__builtin_bit_cast(__hip_bfloat16, s));
}
static __device__ __forceinline__ unsigned cvtpk(float lo, float hi) {
  unsigned d;
  asm("v_cvt_pk_bf16_f32 %0, %1, %2" : "=v"(d) : "v"(lo), "v"(hi));
  return d;
}
static __device__ __forceinline__ void pl32swap(unsigned& a, unsigned& b) {
  uint2v r = __builtin_amdgcn_permlane32_swap(a, b, false, false);
  a = r[0]; b = r[1];
}
static __device__ __forceinline__ short8 mk8(unsigned w0, unsigned w1, unsigned w2, unsigned w3) {
  union { unsigned u[4]; short8 s; } u;
  u.u[0] = w0; u.u[1] = w1; u.u[2] = w2; u.u[3] = w3;
  return u.s;
}
static __device__ __forceinline__ void gload16(const void* g, void* l) {
  __builtin_amdgcn_global_load_lds(
      (const __attribute__((address_space(1))) unsigned int*)g,
      (__attribute__((address_space(3))) unsigned int*)l, 16, 0, 0);
}
#define SW8(l) (((((l) & 7) ^ (((l) >> 3) & 7))) << 3)

// ---------------- Kernel A: fused {weights fp32->bf16 transpose} + {prep/LN} ---
__global__ __launch_bounds__(256) void k_pre(
    const float* __restrict__ query, const float* __restrict__ kv,
    const float* __restrict__ pos,
    const float* __restrict__ qg, const float* __restrict__ qb,
    const float* __restrict__ kg, const float* __restrict__ kb,
    const float* __restrict__ Wq, const float* __restrict__ Wk,
    const float* __restrict__ Wv, const float* __restrict__ Wo,
    short* __restrict__ qn, short* __restrict__ kvn, short* __restrict__ Wt) {
  __shared__ float SM[32 * 516 + 64];
  int bid = blockIdx.x, t = threadIdx.x;

  if (bid >= 512) {
    int cid = bid - 512;
    int m = cid >> 8, k0 = ((cid >> 4) & 15) * 32, n0 = (cid & 15) * 32;
    const float* W = (m == 0) ? Wq : (m == 1) ? Wk : (m == 2) ? Wv : Wo;
    float* T = SM;
    {
      int kl = t >> 3, n4 = (t & 7) * 4;
      float4 v = *(const float4*)(W + (size_t)(k0 + kl) * C_ + n0 + n4);
      T[kl * 33 + n4] = v.x; T[kl * 33 + n4 + 1] = v.y;
      T[kl * 33 + n4 + 2] = v.z; T[kl * 33 + n4 + 3] = v.w;
    }
    __syncthreads();
    {
      int nl = t >> 3, k4 = (t & 7) * 4;
      s4v o;
#pragma unroll
      for (int j = 0; j < 4; ++j) o[j] = f2bf(T[(k4 + j) * 33 + nl]);
      *(s4v*)(Wt + (size_t)(m * C_ + n0 + nl) * C_ + k0 + k4) = o;
    }
    return;
  }

  int l0 = (bid & 63) * 32;
  int b  = (bid >> 6) & 3;
  int z  = bid >> 8;
  const float* src = z ? kv : query;
  const float* g   = z ? kg : qg;
  const float* be  = z ? kb : qb;
  short* dst       = z ? kvn : qn;

  float* T = SM;
  float* mu_s = SM + 32 * 516;
  float* rs_s = mu_s + 32;

#pragma unroll
  for (int i = 0; i < 16; ++i) {
    int c  = i * 32 + (t >> 3);
    int lg = (t & 7) * 4;
    float4 v = *(const float4*)(src + (size_t)(b * C_ + c) * L_ + l0 + lg);
    T[lg * 516 + c] = v.x; T[(lg + 1) * 516 + c] = v.y;
    T[(lg + 2) * 516 + c] = v.z; T[(lg + 3) * 516 + c] = v.w;
  }
  __syncthreads();
#pragma unroll
  for (int i = 0; i < 16; ++i) {
    int flat = i * 256 + t;
    int ll = flat >> 7, c4 = (flat & 127) * 4;
    float4 p = *(const float4*)(pos + (size_t)(l0 + ll) * C_ + c4);
    float4* tp = (float4*)&T[ll * 516 + c4];
    float4 vv = *tp;
    vv.x += p.x; vv.y += p.y; vv.z += p.z; vv.w += p.w;
    *tp = vv;
  }
  __syncthreads();
  {
    int row = t >> 3, j = t & 7;
    float s1 = 0.f, s2 = 0.f;
#pragma unroll
    for (int k = 0; k < 16; ++k) {
      float4 v = *(const float4*)&T[row * 516 + j * 4 + k * 32];
      s1 += v.x + v.y + v.z + v.w;
      s2 += v.x * v.x + v.y * v.y + v.z * v.z + v.w * v.w;
    }
    s1 += __shfl_xor(s1, 1, 64); s2 += __shfl_xor(s2, 1, 64);
    s1 += __shfl_xor(s1, 2, 64); s2 += __shfl_xor(s2, 2, 64);
    s1 += __shfl_xor(s1, 4, 64); s2 += __shfl_xor(s2, 4, 64);
    if (j == 0) {
      float mu  = s1 * (1.0f / C_);
      float var = s2 * (1.0f / C_) - mu * mu;
      mu_s[row] = mu;
      rs_s[row] = rsqrtf(var + EPS_);
    }
  }
  __syncthreads();
#pragma unroll
  for (int i = 0; i < 8; ++i) {
    int row = i * 4 + (t >> 6);
    int c   = (t & 63) * 8;
    float mu = mu_s[row], rs = rs_s[row];
    short8 o;
#pragma unroll
    for (int jj = 0; jj < 8; ++jj) {
      float v = (T[row * 516 + c + jj] - mu) * rs * g[c + jj] + be[c + jj];
      o[jj] = f2bf(v);
    }
    *(short8*)(dst + (size_t)(b * L_ + l0 + row) * C_ + c) = o;
  }
}

// ---------------- Kernel 3: fused QKV GEMM; z==2 writes V^T directly -----------
// Q output pre-scaled by 0.125*log2(e). z==2 epilogue transposes through LDS and
// writes Vtg[b][h][d][l] (the old k_transpose_v, fused).
__global__ __launch_bounds__(256) void k_gemm_qkv(
    const short* __restrict__ qn, const short* __restrict__ kvn,
    const short* __restrict__ Wt,
    const float* __restrict__ bq, const float* __restrict__ bk, const float* __restrict__ bv,
    short* __restrict__ Qw, short* __restrict__ Kw, short* __restrict__ Vtg) {
  int z = blockIdx.z;
  const short* X    = z ? kvn : qn;
  const short* W    = Wt + (size_t)z * C_ * C_;
  const float* bias = (z == 0) ? bq : (z == 1) ? bk : bv;
  float sc          = (z == 0) ? 0.18033688011112042f : 1.0f;  // 0.125*log2(e)

  int m0 = blockIdx.x * 128, n0 = blockIdx.y * 128;
  __shared__ alignas(16) short SMEM[128 * 64 * 2];   // As | Bs ; reused as Tt
  short* As = SMEM;
  short* Bs = SMEM + 128 * 64;
  int t = threadIdx.x, lane = t & 63, w = t >> 6;
  int wm = w & 1, wn = w >> 1;
  int g0 = w * 8 + (lane >> 3);
  int gc = SW8(lane);

  f32x4 zero4 = {0.f, 0.f, 0.f, 0.f};
  f32x4 acc[4][4];
  for (int i = 0; i < 4; ++i) for (int j = 0; j < 4; ++j) acc[i][j] = zero4;

  for (int k0 = 0; k0 < C_; k0 += 64) {
    __syncthreads();
#pragma unroll
    for (int i = 0; i < 4; ++i) {
      int row = i * 32 + g0;
      gload16(X + (size_t)(m0 + row) * C_ + k0 + gc, As + (i * 4 + w) * 512);
      gload16(W + (size_t)(n0 + row) * C_ + k0 + gc, Bs + (i * 4 + w) * 512);
    }
    __syncthreads();
#pragma unroll
    for (int kk = 0; kk < 2; ++kk) {
      short8 a[4], bf[4];
#pragma unroll
      for (int i = 0; i < 4; ++i) {
        int row = wm * 64 + i * 16 + (lane & 15);
        a[i] = *(const short8*)(As + row * 64 + (((kk * 4 + (lane >> 4)) ^ (row & 7)) << 3));
      }
#pragma unroll
      for (int i = 0; i < 4; ++i) {
        int row = wn * 64 + i * 16 + (lane & 15);
        bf[i] = *(const short8*)(Bs + row * 64 + (((kk * 4 + (lane >> 4)) ^ (row & 7)) << 3));
      }
#pragma unroll
      for (int i = 0; i < 4; ++i)
#pragma unroll
        for (int j = 0; j < 4; ++j)
          acc[i][j] = __builtin_amdgcn_mfma_f32_16x16x32_bf16(a[i], bf[j], acc[i][j], 0, 0, 0);
    }
  }

  if (z < 2) {
    short* Y = (z == 0) ? Qw : Kw;
    for (int i = 0; i < 4; ++i)
      for (int j = 0; j < 4; ++j) {
        int colg = n0 + wn * 64 + j * 16 + (lane & 15);
        float bia = bias[colg];
        for (int r = 0; r < 4; ++r) {
          int rowg = m0 + wm * 64 + i * 16 + (lane >> 4) * 4 + r;
          Y[(size_t)rowg * C_ + colg] = f2bf((acc[i][j][r] + bia) * sc);
        }
      }
    return;
  }

  // ---- z == 2: transposed epilogue -> Vtg[b][h][d][l], via LDS (2 passes) ----
  short* Tt = SMEM;   // 64 cols x 136 (128 l + pad) shorts = 17408 B
  int bb = m0 >> 11, lb = m0 & (L_ - 1);
#pragma unroll
  for (int pass = 0; pass < 2; ++pass) {
    __syncthreads();
    if (wn == pass) {
#pragma unroll
      for (int i = 0; i < 4; ++i)
#pragma unroll
        for (int j = 0; j < 4; ++j) {
          int cl = j * 16 + (lane & 15);                 // 0..63 within half
          float bia = bias[n0 + pass * 64 + cl];
          int ll = wm * 64 + i * 16 + (lane >> 4) * 4;   // 4 consecutive l
          s4v o;
#pragma unroll
          for (int r = 0; r < 4; ++r) o[r] = f2bf(acc[i][j][r] + bia);
          *(s4v*)(Tt + cl * 136 + ll) = o;
        }
    }
    __syncthreads();
#pragma unroll
    for (int p = 0; p < 4; ++p) {
      int u = p * 256 + t;
      int c = u >> 4;                // 0..63
      int l8 = (u & 15) * 8;         // 0..120
      int colg = n0 + pass * 64 + c;
      int hh = colg >> 6, dd = colg & 63;
      short8 v = *(short8*)(Tt + c * 136 + l8);
      *(short8*)(Vtg + ((size_t)(bb * H_ + hh) * D_ + dd) * L_ + lb + l8) = v;
    }
  }
}

// ---------------- Kernel 4: attention, 2-deep prefetch, no clamp ---------------
// Wave w: q-block (w>>1)*32, lr-subtile (w&1). 1 barrier/chunk; loads for chunk
// i+2 issued while computing chunk i -> ds_write of chunk i+1 never waits HBM.
#define LDK 72
#define LDV 72

#define GLOADC(CH, KR, VR)                                                        \
  {                                                                               \
    int lr0g = (CH) * 64;                                                         \
    _Pragma("unroll")                                                             \
    for (int p = 0; p < 2; ++p) {                                                 \
      KR[p] = *(const short8*)(Kbase + (size_t)(lr0g + p * 32 + sr) * C_ + sc);   \
      VR[p] = *(const short8*)(Vbase + (size_t)(p * 32 + sr) * L_ + lr0g + sc);   \
    }                                                                             \
  }

#define SWR(BUF, KR, VR)                                                          \
  {                                                                               \
    _Pragma("unroll")                                                             \
    for (int p = 0; p < 2; ++p) {                                                 \
      *(short8*)(&Kt[BUF][(p * 32 + sr) * LDK + sc]) = KR[p];                     \
      *(short8*)(&Vt[BUF][(p * 32 + sr) * LDV + sc]) = VR[p];                     \
    }                                                                             \
  }

#define COMPUTE(BUF)                                                              \
  {                                                                               \
    short8 kf[4], va[2][2];                                                       \
    _Pragma("unroll")                                                             \
    for (int kc = 0; kc < 4; ++kc)                                                \
      kf[kc] = *(const short8*)(&Kt[BUF][(Ts * 32 + l5) * LDK + kc * 16 + hi * 8]); \
    _Pragma("unroll")                                                             \
    for (int dt = 0; dt < 2; ++dt)                                                \
      _Pragma("unroll")                                                           \
      for (int kc = 0; kc < 2; ++kc)                                              \
        va[dt][kc] = *(const short8*)(&Vt[BUF][(dt * 32 + l5) * LDV + (Ts * 2 + kc) * 16 + hi * 8]); \
    f32x16 st;                                                                    \
    _Pragma("unroll")                                                             \
    for (int r = 0; r < 16; ++r) st[r] = 0.f;                                     \
    __builtin_amdgcn_s_setprio(1);                                                \
    _Pragma("unroll")                                                             \
    for (int kc = 0; kc < 4; ++kc)                                                \
      st = __builtin_amdgcn_mfma_f32_32x32x16_bf16(kf[kc], qf[kc], st, 0, 0, 0);  \
    __builtin_amdgcn_s_setprio(0);                                                \
    float ps[16];                                                                 \
    _Pragma("unroll")                                                             \
    for (int r = 0; r < 16; ++r) {                                                \
      float pv = __builtin_amdgcn_exp2f(st[r]);                                   \
      lsum += pv;                                                                 \
      ps[r] = pv;                                                                 \
    }                                                                             \
    short8 pfrag[2];                                                              \
    {                                                                             \
      unsigned d0 = cvtpk(ps[0], ps[1]), d1 = cvtpk(ps[2], ps[3]);                \
      unsigned d2 = cvtpk(ps[4], ps[5]), d3 = cvtpk(ps[6], ps[7]);                \
      pl32swap(d0, d2); pl32swap(d1, d3);                                         \
      pfrag[0] = mk8(d0, d1, d2, d3);                                             \
      unsigned e0 = cvtpk(ps[8], ps[9]), e1 = cvtpk(ps[10], ps[11]);              \
      unsigned e2 = cvtpk(ps[12], ps[13]), e3 = cvtpk(ps[14], ps[15]);            \
      pl32swap(e0, e2); pl32swap(e1, e3);                                         \
      pfrag[1] = mk8(e0, e1, e2, e3);                                             \
    }                                                                             \
    __builtin_amdgcn_s_setprio(1);                                                \
    _Pragma("unroll")                                                             \
    for (int dt = 0; dt < 2; ++dt)                                                \
      _Pragma("unroll")                                                           \
      for (int kc = 0; kc < 2; ++kc)                                              \
        acc[dt] = __builtin_amdgcn_mfma_f32_32x32x16_bf16(va[dt][kc], pfrag[kc], acc[dt], 0, 0, 0); \
    __builtin_amdgcn_s_setprio(0);                                                \
  }

__global__ __launch_bounds__(256, 4) void k_attn(
    const short* __restrict__ Qw, const short* __restrict__ Kw,
    const short* __restrict__ Vtg, short* __restrict__ Ow) {
  int l0 = blockIdx.x * 64;
  int h  = blockIdx.y;
  int b  = blockIdx.z;
  __shared__ alignas(16) short Kt[2][64 * LDK];
  __shared__ alignas(16) short Vt[2][64 * LDV];
  int t = threadIdx.x, lane = t & 63, w = t >> 6;
  int l5 = lane & 31, hi = lane >> 5;
  int Ts = w & 1;

  short8 qf[4];
  {
    int qrow = b * L_ + l0 + (w >> 1) * 32 + l5;
    const short* qp = Qw + ((size_t)qrow * H_ + h) * D_ + hi * 8;
#pragma unroll
    for (int kc = 0; kc < 4; ++kc) qf[kc] = *(const short8*)(qp + kc * 16);
  }

  f32x16 acc[2];
#pragma unroll
  for (int dt = 0; dt < 2; ++dt)
#pragma unroll
    for (int r = 0; r < 16; ++r) acc[dt][r] = 0.f;
  float lsum = 0.f;

  const short* Kbase = Kw + (size_t)(b * L_) * C_ + h * D_;
  const short* Vbase = Vtg + (size_t)(b * H_ + h) * D_ * L_;

  int sr = t >> 3, sc = (t & 7) * 8;

  // prologue: chunk0 -> buf0 (immediate), chunk1 -> regs A
  short8 kA[2], vA[2], kB[2], vB[2];
  GLOADC(0, kA, vA);
  SWR(0, kA, vA);
  GLOADC(1, kA, vA);

  for (int k2 = 0; k2 < 16; ++k2) {
    // ---- window A: chunk 2*k2, reads buf0; writes chunk 2k+1 (regA) -> buf1
    __syncthreads();
    if (k2 < 15) { GLOADC(2 * k2 + 2, kB, vB); }
    COMPUTE(0);
    SWR(1, kA, vA);
    // ---- window B: chunk 2*k2+1, reads buf1; writes chunk 2k+2 (regB) -> buf0
    __syncthreads();
    if (k2 < 15) { GLOADC(2 * k2 + 3, kA, vA); }
    COMPUTE(1);
    if (k2 < 15) { SWR(0, kB, vB); }
  }

  // --- epilogue: pair-reduce (odd wave -> even wave), normalize, store --------
  __syncthreads();
  float* red = (float*)&Kt[0][0];
  if (w & 1) {
    float* dst = red + (w >> 1) * (64 * 34) + lane * 34;
#pragma unroll
    for (int dt = 0; dt < 2; ++dt)
#pragma unroll
      for (int r = 0; r < 16; ++r) dst[dt * 16 + r] = acc[dt][r];
    dst[32] = lsum;
  }
  __syncthreads();
  if (!(w & 1)) {
    const float* srcp = red + (w >> 1) * (64 * 34) + lane * 34;
#pragma unroll
    for (int dt = 0; dt < 2; ++dt)
#pragma unroll
      for (int r = 0; r < 16; ++r) acc[dt][r] += srcp[dt * 16 + r];
    lsum += srcp[32];
    lsum += __shfl_xor(lsum, 32, 64);
    float inv = 1.0f / lsum;
    short* ot = (short*)&Vt[0][0] + (w >> 1) * (32 * 72);
#pragma unroll
    for (int dt = 0; dt < 2; ++dt)
#pragma unroll
      for (int rq = 0; rq < 4; ++rq) {
        s4v o;
#pragma unroll
        for (int j = 0; j < 4; ++j) o[j] = f2bf(acc[dt][rq * 4 + j] * inv);
        *(s4v*)(ot + l5 * 72 + dt * 32 + rq * 8 + hi * 4) = o;
      }
#pragma unroll
    for (int p = 0; p < 4; ++p) {
      int rr = p * 8 + (lane >> 3);
      int c8b = (lane & 7) * 8;
      short8 v = *(const short8*)(ot + rr * 72 + c8b);
      int qg = b * L_ + l0 + (w >> 1) * 32 + rr;
      *(short8*)(Ow + ((size_t)qg * H_ + h) * D_ + c8b) = v;
    }
  }
}

// ---------------- Kernel 5: output projection + bias + residual + transpose ----
__global__ __launch_bounds__(256) void k_gemm_out(
    const short* __restrict__ Ow, const short* __restrict__ Wot,
    const float* __restrict__ bo, const short* __restrict__ qn,
    float* __restrict__ out) {
  int m0 = blockIdx.x * 128, n0 = blockIdx.y * 128;
  __shared__ alignas(16) short As[128 * 64];
  __shared__ alignas(16) short Bs[128 * 64];
  int t = threadIdx.x, lane = t & 63, w = t >> 6;
  int wm = w & 1, wn = w >> 1;
  int g0 = w * 8 + (lane >> 3);
  int gc = SW8(lane);

  f32x4 zero4 = {0.f, 0.f, 0.f, 0.f};
  f32x4 acc[4][4];
  for (int i = 0; i < 4; ++i) for (int j = 0; j < 4; ++j) acc[i][j] = zero4;

  for (int k0 = 0; k0 < C_; k0 += 64) {
    __syncthreads();
#pragma unroll
    for (int i = 0; i < 4; ++i) {
      int row = i * 32 + g0;
      gload16(Ow  + (size_t)(m0 + row) * C_ + k0 + gc, As + (i * 4 + w) * 512);
      gload16(Wot + (size_t)(n0 + row) * C_ + k0 + gc, Bs + (i * 4 + w) * 512);
    }
    __syncthreads();
#pragma unroll
    for (int kk = 0; kk < 2; ++kk) {
      short8 a[4], bf[4];
#pragma unroll
      for (int i = 0; i < 4; ++i) {
        int row = wm * 64 + i * 16 + (lane & 15);
        a[i] = *(const short8*)(As + row * 64 + (((kk * 4 + (lane >> 4)) ^ (row & 7)) << 3));
      }
#pragma unroll
      for (int i = 0; i < 4; ++i) {
        int row = wn * 64 + i * 16 + (lane & 15);
        bf[i] = *(const short8*)(Bs + row * 64 + (((kk * 4 + (lane >> 4)) ^ (row & 7)) << 3));
      }
#pragma unroll
      for (int i = 0; i < 4; ++i)
#pragma unroll
        for (int j = 0; j < 4; ++j)
          acc[i][j] = __builtin_amdgcn_mfma_f32_16x16x32_bf16(a[i], bf[j], acc[i][j], 0, 0, 0);
    }
  }

  for (int i = 0; i < 4; ++i)
    for (int j = 0; j < 4; ++j) {
      int colg = n0 + wn * 64 + j * 16 + (lane & 15);
      float bia = bo[colg];
      for (int r = 0; r < 4; ++r) {
        int rowg = m0 + wm * 64 + i * 16 + (lane >> 4) * 4 + r;
        float val = acc[i][j][r] + bia + bf2f(qn[(size_t)rowg * C_ + colg]);
        int bb = rowg >> 11, l = rowg & (L_ - 1);
        out[((size_t)bb * C_ + colg) * L_ + l] = val;   // (B, C, L)
      }
    }
}

extern "C" void kernel_launch(void* const* d_in, const int* in_sizes, int n_in,
                              void* d_out, int out_size, void* d_ws, size_t ws_size,
                              hipStream_t stream) {
  const float* query     = (const float*)d_in[0];
  const float* key_value = (const float*)d_in[1];
  const float* pos       = (const float*)d_in[2];
  const float* qg        = (const float*)d_in[3];
  const float* qb        = (const float*)d_in[4];
  const float* kg        = (const float*)d_in[5];
  const float* kb        = (const float*)d_in[6];
  const float* Wq        = (const float*)d_in[7];
  const float* bq        = (const float*)d_in[8];
  const float* Wk        = (const float*)d_in[9];
  const float* bk        = (const float*)d_in[10];
  const float* Wv        = (const float*)d_in[11];
  const float* bv        = (const float*)d_in[12];
  const float* Wo        = (const float*)d_in[13];
  const float* bo        = (const float*)d_in[14];
  float* out = (float*)d_out;

  char* ws = (char*)d_ws;
  const size_t SZ = (size_t)B_ * L_ * C_ * 2;   // 8 MB per bf16 (B,L,C) buffer
  short* qn  = (short*)(ws + 0 * SZ);
  short* kvn = (short*)(ws + 1 * SZ);
  short* Qw  = (short*)(ws + 2 * SZ);
  short* Kw  = (short*)(ws + 3 * SZ);
  short* Vtg = (short*)(ws + 4 * SZ);           // V^T [b][h][d][l] (written by gemm z=2)
  short* Ow  = (short*)(ws + 5 * SZ);
  short* Wt  = (short*)(ws + 6 * SZ);           // 4 x 512x512 bf16 = 2 MB

  k_pre<<<dim3(1536), 256, 0, stream>>>(query, key_value, pos, qg, qb, kg, kb,
                                        Wq, Wk, Wv, Wo, qn, kvn, Wt);
  k_gemm_qkv<<<dim3(8192 / 128, C_ / 128, 3), 256, 0, stream>>>(qn, kvn, Wt, bq, bk, bv, Qw, Kw, Vtg);
  k_attn<<<dim3(L_ / 64, H_, B_), 256, 0, stream>>>(Qw, Kw, Vtg, Ow);
  k_gemm_out<<<dim3(8192 / 128, C_ / 128, 1), 256, 0, stream>>>(Ow, Wt + (size_t)3 * C_ * C_, bo, qn, out);
}

// Round 7
// 197.531 us; speedup vs baseline: 1.3301x; 1.3301x over previous
//
#include <hip/hip_runtime.h>
#include <hip/hip_bf16.h>

#define B_ 4
#define C_ 512
#define L_ 2048
#define H_ 8
#define D_ 64
#define EPS_ 1e-5f

using short8 = __attribute__((ext_vector_type(8))) short;
using s4v    = __attribute__((ext_vector_type(4))) short;
using f32x4  = __attribute__((ext_vector_type(4))) float;
using f32x16 = __attribute__((ext_vector_type(16))) float;
using uint2v = __attribute__((ext_vector_type(2))) unsigned int;

static __device__ __forceinline__ short f2bf(float f) {
  __hip_bfloat16 h = __float2bfloat16(f);
  return __builtin_bit_cast(short, h);
}
static __device__ __forceinline__ float bf2f(short s) {
  return __bfloat162float(__builtin_bit_cast(__hip_bfloat16, s));
}
static __device__ __forceinline__ unsigned cvtpk(float lo, float hi) {
  unsigned d;
  asm("v_cvt_pk_bf16_f32 %0, %1, %2" : "=v"(d) : "v"(lo), "v"(hi));
  return d;
}
static __device__ __forceinline__ void pl32swap(unsigned& a, unsigned& b) {
  uint2v r = __builtin_amdgcn_permlane32_swap(a, b, false, false);
  a = r[0]; b = r[1];
}
static __device__ __forceinline__ short8 mk8(unsigned w0, unsigned w1, unsigned w2, unsigned w3) {
  union { unsigned u[4]; short8 s; } u;
  u.u[0] = w0; u.u[1] = w1; u.u[2] = w2; u.u[3] = w3;
  return u.s;
}
static __device__ __forceinline__ void gload16(const void* g, void* l) {
  __builtin_amdgcn_global_load_lds(
      (const __attribute__((address_space(1))) unsigned int*)g,
      (__attribute__((address_space(3))) unsigned int*)l, 16, 0, 0);
}
#define SW8(l) (((((l) & 7) ^ (((l) >> 3) & 7))) << 3)

// ---------------- Kernel A: fused {weights fp32->bf16 transpose} + {prep/LN} ---
__global__ __launch_bounds__(256) void k_pre(
    const float* __restrict__ query, const float* __restrict__ kv,
    const float* __restrict__ pos,
    const float* __restrict__ qg, const float* __restrict__ qb,
    const float* __restrict__ kg, const float* __restrict__ kb,
    const float* __restrict__ Wq, const float* __restrict__ Wk,
    const float* __restrict__ Wv, const float* __restrict__ Wo,
    short* __restrict__ qn, short* __restrict__ kvn, short* __restrict__ Wt) {
  __shared__ float SM[32 * 516 + 64];
  int bid = blockIdx.x, t = threadIdx.x;

  if (bid >= 512) {
    int cid = bid - 512;
    int m = cid >> 8, k0 = ((cid >> 4) & 15) * 32, n0 = (cid & 15) * 32;
    const float* W = (m == 0) ? Wq : (m == 1) ? Wk : (m == 2) ? Wv : Wo;
    float* T = SM;
    {
      int kl = t >> 3, n4 = (t & 7) * 4;
      float4 v = *(const float4*)(W + (size_t)(k0 + kl) * C_ + n0 + n4);
      T[kl * 33 + n4] = v.x; T[kl * 33 + n4 + 1] = v.y;
      T[kl * 33 + n4 + 2] = v.z; T[kl * 33 + n4 + 3] = v.w;
    }
    __syncthreads();
    {
      int nl = t >> 3, k4 = (t & 7) * 4;
      s4v o;
#pragma unroll
      for (int j = 0; j < 4; ++j) o[j] = f2bf(T[(k4 + j) * 33 + nl]);
      *(s4v*)(Wt + (size_t)(m * C_ + n0 + nl) * C_ + k0 + k4) = o;
    }
    return;
  }

  int l0 = (bid & 63) * 32;
  int b  = (bid >> 6) & 3;
  int z  = bid >> 8;
  const float* src = z ? kv : query;
  const float* g   = z ? kg : qg;
  const float* be  = z ? kb : qb;
  short* dst       = z ? kvn : qn;

  float* T = SM;
  float* mu_s = SM + 32 * 516;
  float* rs_s = mu_s + 32;

#pragma unroll
  for (int i = 0; i < 16; ++i) {
    int c  = i * 32 + (t >> 3);
    int lg = (t & 7) * 4;
    float4 v = *(const float4*)(src + (size_t)(b * C_ + c) * L_ + l0 + lg);
    T[lg * 516 + c] = v.x; T[(lg + 1) * 516 + c] = v.y;
    T[(lg + 2) * 516 + c] = v.z; T[(lg + 3) * 516 + c] = v.w;
  }
  __syncthreads();
#pragma unroll
  for (int i = 0; i < 16; ++i) {
    int flat = i * 256 + t;
    int ll = flat >> 7, c4 = (flat & 127) * 4;
    float4 p = *(const float4*)(pos + (size_t)(l0 + ll) * C_ + c4);
    float4* tp = (float4*)&T[ll * 516 + c4];
    float4 vv = *tp;
    vv.x += p.x; vv.y += p.y; vv.z += p.z; vv.w += p.w;
    *tp = vv;
  }
  __syncthreads();
  {
    int row = t >> 3, j = t & 7;
    float s1 = 0.f, s2 = 0.f;
#pragma unroll
    for (int k = 0; k < 16; ++k) {
      float4 v = *(const float4*)&T[row * 516 + j * 4 + k * 32];
      s1 += v.x + v.y + v.z + v.w;
      s2 += v.x * v.x + v.y * v.y + v.z * v.z + v.w * v.w;
    }
    s1 += __shfl_xor(s1, 1, 64); s2 += __shfl_xor(s2, 1, 64);
    s1 += __shfl_xor(s1, 2, 64); s2 += __shfl_xor(s2, 2, 64);
    s1 += __shfl_xor(s1, 4, 64); s2 += __shfl_xor(s2, 4, 64);
    if (j == 0) {
      float mu  = s1 * (1.0f / C_);
      float var = s2 * (1.0f / C_) - mu * mu;
      mu_s[row] = mu;
      rs_s[row] = rsqrtf(var + EPS_);
    }
  }
  __syncthreads();
#pragma unroll
  for (int i = 0; i < 8; ++i) {
    int row = i * 4 + (t >> 6);
    int c   = (t & 63) * 8;
    float mu = mu_s[row], rs = rs_s[row];
    short8 o;
#pragma unroll
    for (int jj = 0; jj < 8; ++jj) {
      float v = (T[row * 516 + c + jj] - mu) * rs * g[c + jj] + be[c + jj];
      o[jj] = f2bf(v);
    }
    *(short8*)(dst + (size_t)(b * L_ + l0 + row) * C_ + c) = o;
  }
}

// ---------------- Kernel 3: fused QKV GEMM; z==2 writes V^T directly -----------
__global__ __launch_bounds__(256) void k_gemm_qkv(
    const short* __restrict__ qn, const short* __restrict__ kvn,
    const short* __restrict__ Wt,
    const float* __restrict__ bq, const float* __restrict__ bk, const float* __restrict__ bv,
    short* __restrict__ Qw, short* __restrict__ Kw, short* __restrict__ Vtg) {
  int z = blockIdx.z;
  const short* X    = z ? kvn : qn;
  const short* W    = Wt + (size_t)z * C_ * C_;
  const float* bias = (z == 0) ? bq : (z == 1) ? bk : bv;
  float sc          = (z == 0) ? 0.18033688011112042f : 1.0f;  // 0.125*log2(e)

  int m0 = blockIdx.x * 128, n0 = blockIdx.y * 128;
  __shared__ alignas(16) short SMEM[128 * 64 * 2];   // As | Bs ; reused as Tt
  short* As = SMEM;
  short* Bs = SMEM + 128 * 64;
  int t = threadIdx.x, lane = t & 63, w = t >> 6;
  int wm = w & 1, wn = w >> 1;
  int g0 = w * 8 + (lane >> 3);
  int gc = SW8(lane);

  f32x4 zero4 = {0.f, 0.f, 0.f, 0.f};
  f32x4 acc[4][4];
  for (int i = 0; i < 4; ++i) for (int j = 0; j < 4; ++j) acc[i][j] = zero4;

  for (int k0 = 0; k0 < C_; k0 += 64) {
    __syncthreads();
#pragma unroll
    for (int i = 0; i < 4; ++i) {
      int row = i * 32 + g0;
      gload16(X + (size_t)(m0 + row) * C_ + k0 + gc, As + (i * 4 + w) * 512);
      gload16(W + (size_t)(n0 + row) * C_ + k0 + gc, Bs + (i * 4 + w) * 512);
    }
    __syncthreads();
#pragma unroll
    for (int kk = 0; kk < 2; ++kk) {
      short8 a[4], bf[4];
#pragma unroll
      for (int i = 0; i < 4; ++i) {
        int row = wm * 64 + i * 16 + (lane & 15);
        a[i] = *(const short8*)(As + row * 64 + (((kk * 4 + (lane >> 4)) ^ (row & 7)) << 3));
      }
#pragma unroll
      for (int i = 0; i < 4; ++i) {
        int row = wn * 64 + i * 16 + (lane & 15);
        bf[i] = *(const short8*)(Bs + row * 64 + (((kk * 4 + (lane >> 4)) ^ (row & 7)) << 3));
      }
#pragma unroll
      for (int i = 0; i < 4; ++i)
#pragma unroll
        for (int j = 0; j < 4; ++j)
          acc[i][j] = __builtin_amdgcn_mfma_f32_16x16x32_bf16(a[i], bf[j], acc[i][j], 0, 0, 0);
    }
  }

  if (z < 2) {
    short* Y = (z == 0) ? Qw : Kw;
    for (int i = 0; i < 4; ++i)
      for (int j = 0; j < 4; ++j) {
        int colg = n0 + wn * 64 + j * 16 + (lane & 15);
        float bia = bias[colg];
        for (int r = 0; r < 4; ++r) {
          int rowg = m0 + wm * 64 + i * 16 + (lane >> 4) * 4 + r;
          Y[(size_t)rowg * C_ + colg] = f2bf((acc[i][j][r] + bia) * sc);
        }
      }
    return;
  }

  // ---- z == 2: transposed epilogue -> Vtg[b][h][d][l], via LDS (2 passes) ----
  short* Tt = SMEM;   // 64 cols x 136 (128 l + pad) shorts
  int bb = m0 >> 11, lb = m0 & (L_ - 1);
#pragma unroll
  for (int pass = 0; pass < 2; ++pass) {
    __syncthreads();
    if (wn == pass) {
#pragma unroll
      for (int i = 0; i < 4; ++i)
#pragma unroll
        for (int j = 0; j < 4; ++j) {
          int cl = j * 16 + (lane & 15);
          float bia = bias[n0 + pass * 64 + cl];
          int ll = wm * 64 + i * 16 + (lane >> 4) * 4;
          s4v o;
#pragma unroll
          for (int r = 0; r < 4; ++r) o[r] = f2bf(acc[i][j][r] + bia);
          *(s4v*)(Tt + cl * 136 + ll) = o;
        }
    }
    __syncthreads();
#pragma unroll
    for (int p = 0; p < 4; ++p) {
      int u = p * 256 + t;
      int c = u >> 4;
      int l8 = (u & 15) * 8;
      int colg = n0 + pass * 64 + c;
      int hh = colg >> 6, dd = colg & 63;
      short8 v = *(short8*)(Tt + c * 136 + l8);
      *(short8*)(Vtg + ((size_t)(bb * H_ + hh) * D_ + dd) * L_ + lb + l8) = v;
    }
  }
}

// ---------------- Kernel 4: attention (round-1 structure, clamp removed) -------
// Q-tile 128, 4 waves x 32 q-rows. Per 64-lr chunk: S^T=K.Q^T (2 tiles),
// softmax in-register (exp2, no clamp), P^T via cvt_pk+permlane32_swap,
// O^T += V^T.P^T. K/V double-buffered in LDS, 1 barrier/chunk, T14 split.
#define LDK 72
#define LDV 72
__global__ __launch_bounds__(256, 2) void k_attn(
    const short* __restrict__ Qw, const short* __restrict__ Kw,
    const short* __restrict__ Vtg, short* __restrict__ Ow) {
  int l0 = blockIdx.x * 128;
  int h  = blockIdx.y;
  int b  = blockIdx.z;
  __shared__ alignas(16) short Kt[2][64 * LDK];
  __shared__ alignas(16) short Vt[2][64 * LDV];
  int t = threadIdx.x, lane = t & 63, w = t >> 6;
  int l5 = lane & 31, hi = lane >> 5;

  short8 qf[4];
  {
    int qrow = b * L_ + l0 + w * 32 + l5;
    const short* qp = Qw + ((size_t)qrow * H_ + h) * D_ + hi * 8;
#pragma unroll
    for (int kc = 0; kc < 4; ++kc) qf[kc] = *(const short8*)(qp + kc * 16);
  }

  f32x16 acc[2];
#pragma unroll
  for (int dt = 0; dt < 2; ++dt)
#pragma unroll
    for (int r = 0; r < 16; ++r) acc[dt][r] = 0.f;
  float lsum = 0.f;

  const short* Kbase = Kw + (size_t)(b * L_) * C_ + h * D_;
  const short* Vbase = Vtg + (size_t)(b * H_ + h) * D_ * L_;

  int sr = t >> 3, sc = (t & 7) * 8;

  // stage chunk 0 into buffer 0
  {
    short8 kr[2], vr[2];
#pragma unroll
    for (int p = 0; p < 2; ++p) {
      kr[p] = *(const short8*)(Kbase + (size_t)(p * 32 + sr) * C_ + sc);
      vr[p] = *(const short8*)(Vbase + (size_t)(p * 32 + sr) * L_ + sc);
    }
#pragma unroll
    for (int p = 0; p < 2; ++p) {
      *(short8*)(&Kt[0][(p * 32 + sr) * LDK + sc]) = kr[p];
      *(short8*)(&Vt[0][(p * 32 + sr) * LDV + sc]) = vr[p];
    }
  }

  int cur = 0;
  for (int it = 0; it < 32; ++it) {
    __syncthreads();
    short8 kn[2], vn[2];
    if (it < 31) {
      int lr0 = (it + 1) * 64;
#pragma unroll
      for (int p = 0; p < 2; ++p) {
        kn[p] = *(const short8*)(Kbase + (size_t)(lr0 + p * 32 + sr) * C_ + sc);
        vn[p] = *(const short8*)(Vbase + (size_t)(p * 32 + sr) * L_ + lr0 + sc);
      }
    }
    const short* KT = &Kt[cur][0];
    const short* VT = &Vt[cur][0];

    // --- S^T = K . Q^T   (2 lr-tiles of 32)
    f32x16 st[2];
#pragma unroll
    for (int T = 0; T < 2; ++T)
#pragma unroll
      for (int r = 0; r < 16; ++r) st[T][r] = 0.f;
    __builtin_amdgcn_s_setprio(1);
#pragma unroll
    for (int T = 0; T < 2; ++T)
#pragma unroll
      for (int kc = 0; kc < 4; ++kc) {
        short8 kf = *(const short8*)(KT + (T * 32 + l5) * LDK + kc * 16 + hi * 8);
        st[T] = __builtin_amdgcn_mfma_f32_32x32x16_bf16(kf, qf[kc], st[T], 0, 0, 0);
      }
    __builtin_amdgcn_s_setprio(0);

    // V^T fragments issued now: lgkm latency hides under softmax VALU
    short8 va[2][4];
#pragma unroll
    for (int dt = 0; dt < 2; ++dt)
#pragma unroll
      for (int kc = 0; kc < 4; ++kc)
        va[dt][kc] = *(const short8*)(VT + (dt * 32 + l5) * LDV + kc * 16 + hi * 8);

    // --- softmax (unnormalized, no clamp) + pack P^T frags in-register
    short8 pfrag[2][2];
#pragma unroll
    for (int T = 0; T < 2; ++T) {
      float ps[16];
#pragma unroll
      for (int r = 0; r < 16; ++r) {
        float pv = __builtin_amdgcn_exp2f(st[T][r]);
        lsum += pv;
        ps[r] = pv;
      }
      unsigned d0 = cvtpk(ps[0], ps[1]),   d1 = cvtpk(ps[2], ps[3]);
      unsigned d2 = cvtpk(ps[4], ps[5]),   d3 = cvtpk(ps[6], ps[7]);
      pl32swap(d0, d2); pl32swap(d1, d3);
      pfrag[T][0] = mk8(d0, d1, d2, d3);
      unsigned e0 = cvtpk(ps[8], ps[9]),   e1 = cvtpk(ps[10], ps[11]);
      unsigned e2 = cvtpk(ps[12], ps[13]), e3 = cvtpk(ps[14], ps[15]);
      pl32swap(e0, e2); pl32swap(e1, e3);
      pfrag[T][1] = mk8(e0, e1, e2, e3);
    }

    // --- O^T += V^T . P^T
    __builtin_amdgcn_s_setprio(1);
#pragma unroll
    for (int dt = 0; dt < 2; ++dt)
#pragma unroll
      for (int T = 0; T < 2; ++T)
#pragma unroll
        for (int kc = 0; kc < 2; ++kc)
          acc[dt] = __builtin_amdgcn_mfma_f32_32x32x16_bf16(va[dt][T * 2 + kc], pfrag[T][kc], acc[dt], 0, 0, 0);
    __builtin_amdgcn_s_setprio(0);

    if (it < 31) {
#pragma unroll
      for (int p = 0; p < 2; ++p) {
        *(short8*)(&Kt[cur ^ 1][(p * 32 + sr) * LDK + sc]) = kn[p];
        *(short8*)(&Vt[cur ^ 1][(p * 32 + sr) * LDV + sc]) = vn[p];
      }
    }
    cur ^= 1;
  }

  // --- epilogue: normalize, transpose O^T->O via per-wave LDS, coalesced store
  __syncthreads();
  lsum += __shfl_xor(lsum, 32, 64);
  float inv = 1.0f / lsum;
  short* ot = (short*)&Kt[0][0] + w * (32 * 72);
#pragma unroll
  for (int dt = 0; dt < 2; ++dt)
#pragma unroll
    for (int rq = 0; rq < 4; ++rq) {
      s4v o;
#pragma unroll
      for (int j = 0; j < 4; ++j) o[j] = f2bf(acc[dt][rq * 4 + j] * inv);
      *(s4v*)(ot + l5 * 72 + dt * 32 + rq * 8 + hi * 4) = o;
    }
  __syncthreads();
#pragma unroll
  for (int p = 0; p < 4; ++p) {
    int rr = p * 8 + (lane >> 3);
    int c8b = (lane & 7) * 8;
    short8 v = *(const short8*)(ot + rr * 72 + c8b);
    int qg = b * L_ + l0 + w * 32 + rr;
    *(short8*)(Ow + ((size_t)qg * H_ + h) * D_ + c8b) = v;
  }
}

// ---------------- Kernel 5: output projection + bias + residual + transpose ----
__global__ __launch_bounds__(256) void k_gemm_out(
    const short* __restrict__ Ow, const short* __restrict__ Wot,
    const float* __restrict__ bo, const short* __restrict__ qn,
    float* __restrict__ out) {
  int m0 = blockIdx.x * 128, n0 = blockIdx.y * 128;
  __shared__ alignas(16) short As[128 * 64];
  __shared__ alignas(16) short Bs[128 * 64];
  int t = threadIdx.x, lane = t & 63, w = t >> 6;
  int wm = w & 1, wn = w >> 1;
  int g0 = w * 8 + (lane >> 3);
  int gc = SW8(lane);

  f32x4 zero4 = {0.f, 0.f, 0.f, 0.f};
  f32x4 acc[4][4];
  for (int i = 0; i < 4; ++i) for (int j = 0; j < 4; ++j) acc[i][j] = zero4;

  for (int k0 = 0; k0 < C_; k0 += 64) {
    __syncthreads();
#pragma unroll
    for (int i = 0; i < 4; ++i) {
      int row = i * 32 + g0;
      gload16(Ow  + (size_t)(m0 + row) * C_ + k0 + gc, As + (i * 4 + w) * 512);
      gload16(Wot + (size_t)(n0 + row) * C_ + k0 + gc, Bs + (i * 4 + w) * 512);
    }
    __syncthreads();
#pragma unroll
    for (int kk = 0; kk < 2; ++kk) {
      short8 a[4], bf[4];
#pragma unroll
      for (int i = 0; i < 4; ++i) {
        int row = wm * 64 + i * 16 + (lane & 15);
        a[i] = *(const short8*)(As + row * 64 + (((kk * 4 + (lane >> 4)) ^ (row & 7)) << 3));
      }
#pragma unroll
      for (int i = 0; i < 4; ++i) {
        int row = wn * 64 + i * 16 + (lane & 15);
        bf[i] = *(const short8*)(Bs + row * 64 + (((kk * 4 + (lane >> 4)) ^ (row & 7)) << 3));
      }
#pragma unroll
      for (int i = 0; i < 4; ++i)
#pragma unroll
        for (int j = 0; j < 4; ++j)
          acc[i][j] = __builtin_amdgcn_mfma_f32_16x16x32_bf16(a[i], bf[j], acc[i][j], 0, 0, 0);
    }
  }

  for (int i = 0; i < 4; ++i)
    for (int j = 0; j < 4; ++j) {
      int colg = n0 + wn * 64 + j * 16 + (lane & 15);
      float bia = bo[colg];
      for (int r = 0; r < 4; ++r) {
        int rowg = m0 + wm * 64 + i * 16 + (lane >> 4) * 4 + r;
        float val = acc[i][j][r] + bia + bf2f(qn[(size_t)rowg * C_ + colg]);
        int bb = rowg >> 11, l = rowg & (L_ - 1);
        out[((size_t)bb * C_ + colg) * L_ + l] = val;   // (B, C, L)
      }
    }
}

extern "C" void kernel_launch(void* const* d_in, const int* in_sizes, int n_in,
                              void* d_out, int out_size, void* d_ws, size_t ws_size,
                              hipStream_t stream) {
  const float* query     = (const float*)d_in[0];
  const float* key_value = (const float*)d_in[1];
  const float* pos       = (const float*)d_in[2];
  const float* qg        = (const float*)d_in[3];
  const float* qb        = (const float*)d_in[4];
  const float* kg        = (const float*)d_in[5];
  const float* kb        = (const float*)d_in[6];
  const float* Wq        = (const float*)d_in[7];
  const float* bq        = (const float*)d_in[8];
  const float* Wk        = (const float*)d_in[9];
  const float* bk        = (const float*)d_in[10];
  const float* Wv        = (const float*)d_in[11];
  const float* bv        = (const float*)d_in[12];
  const float* Wo        = (const float*)d_in[13];
  const float* bo        = (const float*)d_in[14];
  float* out = (float*)d_out;

  char* ws = (char*)d_ws;
  const size_t SZ = (size_t)B_ * L_ * C_ * 2;   // 8 MB per bf16 (B,L,C) buffer
  short* qn  = (short*)(ws + 0 * SZ);
  short* kvn = (short*)(ws + 1 * SZ);
  short* Qw  = (short*)(ws + 2 * SZ);
  short* Kw  = (short*)(ws + 3 * SZ);
  short* Vtg = (short*)(ws + 4 * SZ);           // V^T [b][h][d][l] (written by gemm z=2)
  short* Ow  = (short*)(ws + 5 * SZ);
  short* Wt  = (short*)(ws + 6 * SZ);           // 4 x 512x512 bf16 = 2 MB

  k_pre<<<dim3(1536), 256, 0, stream>>>(query, key_value, pos, qg, qb, kg, kb,
                                        Wq, Wk, Wv, Wo, qn, kvn, Wt);
  k_gemm_qkv<<<dim3(8192 / 128, C_ / 128, 3), 256, 0, stream>>>(qn, kvn, Wt, bq, bk, bv, Qw, Kw, Vtg);
  k_attn<<<dim3(L_ / 128, H_, B_), 256, 0, stream>>>(Qw, Kw, Vtg, Ow);
  k_gemm_out<<<dim3(8192 / 128, C_ / 128, 1), 256, 0, stream>>>(Ow, Wt + (size_t)3 * C_ * C_, bo, qn, out);
}

// Round 8
// 196.600 us; speedup vs baseline: 1.3364x; 1.0047x over previous
//
#include <hip/hip_runtime.h>
#include <hip/hip_bf16.h>

#define B_ 4
#define C_ 512
#define L_ 2048
#define H_ 8
#define D_ 64
#define EPS_ 1e-5f

using short8 = __attribute__((ext_vector_type(8))) short;
using s4v    = __attribute__((ext_vector_type(4))) short;
using f32x4  = __attribute__((ext_vector_type(4))) float;
using f32x16 = __attribute__((ext_vector_type(16))) float;
using uint2v = __attribute__((ext_vector_type(2))) unsigned int;

static __device__ __forceinline__ short f2bf(float f) {
  __hip_bfloat16 h = __float2bfloat16(f);
  return __builtin_bit_cast(short, h);
}
static __device__ __forceinline__ float bf2f(short s) {
  return __bfloat162float(__builtin_bit_cast(__hip_bfloat16, s));
}
static __device__ __forceinline__ unsigned cvtpk(float lo, float hi) {
  unsigned d;
  asm("v_cvt_pk_bf16_f32 %0, %1, %2" : "=v"(d) : "v"(lo), "v"(hi));
  return d;
}
static __device__ __forceinline__ void pl32swap(unsigned& a, unsigned& b) {
  uint2v r = __builtin_amdgcn_permlane32_swap(a, b, false, false);
  a = r[0]; b = r[1];
}
static __device__ __forceinline__ short8 mk8(unsigned w0, unsigned w1, unsigned w2, unsigned w3) {
  union { unsigned u[4]; short8 s; } u;
  u.u[0] = w0; u.u[1] = w1; u.u[2] = w2; u.u[3] = w3;
  return u.s;
}
static __device__ __forceinline__ void gload16(const void* g, void* l) {
  __builtin_amdgcn_global_load_lds(
      (const __attribute__((address_space(1))) unsigned int*)g,
      (__attribute__((address_space(3))) unsigned int*)l, 16, 0, 0);
}
#define SW8(l) (((((l) & 7) ^ (((l) >> 3) & 7))) << 3)

// ---------------- Kernel A: fused {weights fp32->bf16 transpose} + {prep/LN} ---
// pos-add fused into the stats pass (one fewer LDS pass + barrier).
__global__ __launch_bounds__(256) void k_pre(
    const float* __restrict__ query, const float* __restrict__ kv,
    const float* __restrict__ pos,
    const float* __restrict__ qg, const float* __restrict__ qb,
    const float* __restrict__ kg, const float* __restrict__ kb,
    const float* __restrict__ Wq, const float* __restrict__ Wk,
    const float* __restrict__ Wv, const float* __restrict__ Wo,
    short* __restrict__ qn, short* __restrict__ kvn, short* __restrict__ Wt) {
  __shared__ float SM[32 * 516 + 64];
  int bid = blockIdx.x, t = threadIdx.x;

  if (bid >= 512) {
    int cid = bid - 512;
    int m = cid >> 8, k0 = ((cid >> 4) & 15) * 32, n0 = (cid & 15) * 32;
    const float* W = (m == 0) ? Wq : (m == 1) ? Wk : (m == 2) ? Wv : Wo;
    float* T = SM;
    {
      int kl = t >> 3, n4 = (t & 7) * 4;
      float4 v = *(const float4*)(W + (size_t)(k0 + kl) * C_ + n0 + n4);
      T[kl * 33 + n4] = v.x; T[kl * 33 + n4 + 1] = v.y;
      T[kl * 33 + n4 + 2] = v.z; T[kl * 33 + n4 + 3] = v.w;
    }
    __syncthreads();
    {
      int nl = t >> 3, k4 = (t & 7) * 4;
      s4v o;
#pragma unroll
      for (int j = 0; j < 4; ++j) o[j] = f2bf(T[(k4 + j) * 33 + nl]);
      *(s4v*)(Wt + (size_t)(m * C_ + n0 + nl) * C_ + k0 + k4) = o;
    }
    return;
  }

  int l0 = (bid & 63) * 32;
  int b  = (bid >> 6) & 3;
  int z  = bid >> 8;
  const float* src = z ? kv : query;
  const float* g   = z ? kg : qg;
  const float* be  = z ? kb : qb;
  short* dst       = z ? kvn : qn;

  float* T = SM;
  float* mu_s = SM + 32 * 516;
  float* rs_s = mu_s + 32;

#pragma unroll
  for (int i = 0; i < 16; ++i) {
    int c  = i * 32 + (t >> 3);
    int lg = (t & 7) * 4;
    float4 v = *(const float4*)(src + (size_t)(b * C_ + c) * L_ + l0 + lg);
    T[lg * 516 + c] = v.x; T[(lg + 1) * 516 + c] = v.y;
    T[(lg + 2) * 516 + c] = v.z; T[(lg + 3) * 516 + c] = v.w;
  }
  __syncthreads();
  // stats pass with fused pos-add (read T, add pos, write back, accumulate)
  {
    int row = t >> 3, j = t & 7;
    const float* prow = pos + (size_t)(l0 + row) * C_;
    float s1 = 0.f, s2 = 0.f;
#pragma unroll
    for (int k = 0; k < 16; ++k) {
      int c4 = j * 4 + k * 32;
      float4 v = *(const float4*)&T[row * 516 + c4];
      float4 p = *(const float4*)(prow + c4);
      v.x += p.x; v.y += p.y; v.z += p.z; v.w += p.w;
      *(float4*)&T[row * 516 + c4] = v;
      s1 += v.x + v.y + v.z + v.w;
      s2 += v.x * v.x + v.y * v.y + v.z * v.z + v.w * v.w;
    }
    s1 += __shfl_xor(s1, 1, 64); s2 += __shfl_xor(s2, 1, 64);
    s1 += __shfl_xor(s1, 2, 64); s2 += __shfl_xor(s2, 2, 64);
    s1 += __shfl_xor(s1, 4, 64); s2 += __shfl_xor(s2, 4, 64);
    if (j == 0) {
      float mu  = s1 * (1.0f / C_);
      float var = s2 * (1.0f / C_) - mu * mu;
      mu_s[row] = mu;
      rs_s[row] = rsqrtf(var + EPS_);
    }
  }
  __syncthreads();
#pragma unroll
  for (int i = 0; i < 8; ++i) {
    int row = i * 4 + (t >> 6);
    int c   = (t & 63) * 8;
    float mu = mu_s[row], rs = rs_s[row];
    short8 o;
#pragma unroll
    for (int jj = 0; jj < 8; ++jj) {
      float v = (T[row * 516 + c + jj] - mu) * rs * g[c + jj] + be[c + jj];
      o[jj] = f2bf(v);
    }
    *(short8*)(dst + (size_t)(b * L_ + l0 + row) * C_ + c) = o;
  }
}

// ---------------- Kernel 3: fused QKV GEMM; z==2 writes V^T directly -----------
__global__ __launch_bounds__(256) void k_gemm_qkv(
    const short* __restrict__ qn, const short* __restrict__ kvn,
    const short* __restrict__ Wt,
    const float* __restrict__ bq, const float* __restrict__ bk, const float* __restrict__ bv,
    short* __restrict__ Qw, short* __restrict__ Kw, short* __restrict__ Vtg) {
  int z = blockIdx.z;
  const short* X    = z ? kvn : qn;
  const short* W    = Wt + (size_t)z * C_ * C_;
  const float* bias = (z == 0) ? bq : (z == 1) ? bk : bv;
  float sc          = (z == 0) ? 0.18033688011112042f : 1.0f;  // 0.125*log2(e)

  int m0 = blockIdx.x * 128, n0 = blockIdx.y * 128;
  __shared__ alignas(16) short SMEM[128 * 64 * 2];   // As | Bs ; reused as Tt
  short* As = SMEM;
  short* Bs = SMEM + 128 * 64;
  int t = threadIdx.x, lane = t & 63, w = t >> 6;
  int wm = w & 1, wn = w >> 1;
  int g0 = w * 8 + (lane >> 3);
  int gc = SW8(lane);

  f32x4 zero4 = {0.f, 0.f, 0.f, 0.f};
  f32x4 acc[4][4];
  for (int i = 0; i < 4; ++i) for (int j = 0; j < 4; ++j) acc[i][j] = zero4;

  for (int k0 = 0; k0 < C_; k0 += 64) {
    __syncthreads();
#pragma unroll
    for (int i = 0; i < 4; ++i) {
      int row = i * 32 + g0;
      gload16(X + (size_t)(m0 + row) * C_ + k0 + gc, As + (i * 4 + w) * 512);
      gload16(W + (size_t)(n0 + row) * C_ + k0 + gc, Bs + (i * 4 + w) * 512);
    }
    __syncthreads();
#pragma unroll
    for (int kk = 0; kk < 2; ++kk) {
      short8 a[4], bf[4];
#pragma unroll
      for (int i = 0; i < 4; ++i) {
        int row = wm * 64 + i * 16 + (lane & 15);
        a[i] = *(const short8*)(As + row * 64 + (((kk * 4 + (lane >> 4)) ^ (row & 7)) << 3));
      }
#pragma unroll
      for (int i = 0; i < 4; ++i) {
        int row = wn * 64 + i * 16 + (lane & 15);
        bf[i] = *(const short8*)(Bs + row * 64 + (((kk * 4 + (lane >> 4)) ^ (row & 7)) << 3));
      }
#pragma unroll
      for (int i = 0; i < 4; ++i)
#pragma unroll
        for (int j = 0; j < 4; ++j)
          acc[i][j] = __builtin_amdgcn_mfma_f32_16x16x32_bf16(a[i], bf[j], acc[i][j], 0, 0, 0);
    }
  }

  if (z < 2) {
    short* Y = (z == 0) ? Qw : Kw;
    for (int i = 0; i < 4; ++i)
      for (int j = 0; j < 4; ++j) {
        int colg = n0 + wn * 64 + j * 16 + (lane & 15);
        float bia = bias[colg];
        for (int r = 0; r < 4; ++r) {
          int rowg = m0 + wm * 64 + i * 16 + (lane >> 4) * 4 + r;
          Y[(size_t)rowg * C_ + colg] = f2bf((acc[i][j][r] + bia) * sc);
        }
      }
    return;
  }

  // ---- z == 2: transposed epilogue -> Vtg[b][h][d][l], via LDS (2 passes) ----
  short* Tt = SMEM;   // 64 cols x 136 (128 l + pad) shorts
  int bb = m0 >> 11, lb = m0 & (L_ - 1);
#pragma unroll
  for (int pass = 0; pass < 2; ++pass) {
    __syncthreads();
    if (wn == pass) {
#pragma unroll
      for (int i = 0; i < 4; ++i)
#pragma unroll
        for (int j = 0; j < 4; ++j) {
          int cl = j * 16 + (lane & 15);
          float bia = bias[n0 + pass * 64 + cl];
          int ll = wm * 64 + i * 16 + (lane >> 4) * 4;
          s4v o;
#pragma unroll
          for (int r = 0; r < 4; ++r) o[r] = f2bf(acc[i][j][r] + bia);
          *(s4v*)(Tt + cl * 136 + ll) = o;
        }
    }
    __syncthreads();
#pragma unroll
    for (int p = 0; p < 4; ++p) {
      int u = p * 256 + t;
      int c = u >> 4;
      int l8 = (u & 15) * 8;
      int colg = n0 + pass * 64 + c;
      int hh = colg >> 6, dd = colg & 63;
      short8 v = *(short8*)(Tt + c * 136 + l8);
      *(short8*)(Vtg + ((size_t)(bb * H_ + hh) * D_ + dd) * L_ + lb + l8) = v;
    }
  }
}

// ---------------- Kernel 4: attention (round-7 structure + XCD swizzle) --------
#define LDK 72
#define LDV 72
__global__ __launch_bounds__(256, 2) void k_attn(
    const short* __restrict__ Qw, const short* __restrict__ Kw,
    const short* __restrict__ Vtg, short* __restrict__ Ow) {
  // XCD-aware bijective remap: physical p -> logical lg = (p&7)*64 + p>>3.
  // XCD k (p%8==k) then owns lg in [64k,64k+64): 4 (h,b) pairs x all 16 q-tiles
  // -> K/V working set 2 MB per XCD L2 (was: same head scattered over 8 XCDs).
  int p  = blockIdx.x + 16 * (blockIdx.y + 8 * blockIdx.z);
  int lg = ((p & 7) << 6) | (p >> 3);
  int l0 = (lg & 15) * 128;
  int h  = (lg >> 4) & 7;
  int b  = lg >> 7;
  __shared__ alignas(16) short Kt[2][64 * LDK];
  __shared__ alignas(16) short Vt[2][64 * LDV];
  int t = threadIdx.x, lane = t & 63, w = t >> 6;
  int l5 = lane & 31, hi = lane >> 5;

  short8 qf[4];
  {
    int qrow = b * L_ + l0 + w * 32 + l5;
    const short* qp = Qw + ((size_t)qrow * H_ + h) * D_ + hi * 8;
#pragma unroll
    for (int kc = 0; kc < 4; ++kc) qf[kc] = *(const short8*)(qp + kc * 16);
  }

  f32x16 acc[2];
#pragma unroll
  for (int dt = 0; dt < 2; ++dt)
#pragma unroll
    for (int r = 0; r < 16; ++r) acc[dt][r] = 0.f;
  float lsum = 0.f;

  const short* Kbase = Kw + (size_t)(b * L_) * C_ + h * D_;
  const short* Vbase = Vtg + (size_t)(b * H_ + h) * D_ * L_;

  int sr = t >> 3, sc = (t & 7) * 8;

  // stage chunk 0 into buffer 0
  {
    short8 kr[2], vr[2];
#pragma unroll
    for (int pp = 0; pp < 2; ++pp) {
      kr[pp] = *(const short8*)(Kbase + (size_t)(pp * 32 + sr) * C_ + sc);
      vr[pp] = *(const short8*)(Vbase + (size_t)(pp * 32 + sr) * L_ + sc);
    }
#pragma unroll
    for (int pp = 0; pp < 2; ++pp) {
      *(short8*)(&Kt[0][(pp * 32 + sr) * LDK + sc]) = kr[pp];
      *(short8*)(&Vt[0][(pp * 32 + sr) * LDV + sc]) = vr[pp];
    }
  }

  int cur = 0;
  for (int it = 0; it < 32; ++it) {
    __syncthreads();
    short8 kn[2], vn[2];
    if (it < 31) {
      int lr0 = (it + 1) * 64;
#pragma unroll
      for (int pp = 0; pp < 2; ++pp) {
        kn[pp] = *(const short8*)(Kbase + (size_t)(lr0 + pp * 32 + sr) * C_ + sc);
        vn[pp] = *(const short8*)(Vbase + (size_t)(pp * 32 + sr) * L_ + lr0 + sc);
      }
    }
    const short* KT = &Kt[cur][0];
    const short* VT = &Vt[cur][0];

    // --- S^T = K . Q^T   (2 lr-tiles of 32)
    f32x16 st[2];
#pragma unroll
    for (int T = 0; T < 2; ++T)
#pragma unroll
      for (int r = 0; r < 16; ++r) st[T][r] = 0.f;
    __builtin_amdgcn_s_setprio(1);
#pragma unroll
    for (int T = 0; T < 2; ++T)
#pragma unroll
      for (int kc = 0; kc < 4; ++kc) {
        short8 kf = *(const short8*)(KT + (T * 32 + l5) * LDK + kc * 16 + hi * 8);
        st[T] = __builtin_amdgcn_mfma_f32_32x32x16_bf16(kf, qf[kc], st[T], 0, 0, 0);
      }
    __builtin_amdgcn_s_setprio(0);

    // V^T fragments issued now: lgkm latency hides under softmax VALU
    short8 va[2][4];
#pragma unroll
    for (int dt = 0; dt < 2; ++dt)
#pragma unroll
      for (int kc = 0; kc < 4; ++kc)
        va[dt][kc] = *(const short8*)(VT + (dt * 32 + l5) * LDV + kc * 16 + hi * 8);

    // --- softmax (unnormalized, no clamp) + pack P^T frags in-register
    short8 pfrag[2][2];
#pragma unroll
    for (int T = 0; T < 2; ++T) {
      float ps[16];
#pragma unroll
      for (int r = 0; r < 16; ++r) {
        float pv = __builtin_amdgcn_exp2f(st[T][r]);
        lsum += pv;
        ps[r] = pv;
      }
      unsigned d0 = cvtpk(ps[0], ps[1]),   d1 = cvtpk(ps[2], ps[3]);
      unsigned d2 = cvtpk(ps[4], ps[5]),   d3 = cvtpk(ps[6], ps[7]);
      pl32swap(d0, d2); pl32swap(d1, d3);
      pfrag[T][0] = mk8(d0, d1, d2, d3);
      unsigned e0 = cvtpk(ps[8], ps[9]),   e1 = cvtpk(ps[10], ps[11]);
      unsigned e2 = cvtpk(ps[12], ps[13]), e3 = cvtpk(ps[14], ps[15]);
      pl32swap(e0, e2); pl32swap(e1, e3);
      pfrag[T][1] = mk8(e0, e1, e2, e3);
    }

    // --- O^T += V^T . P^T
    __builtin_amdgcn_s_setprio(1);
#pragma unroll
    for (int dt = 0; dt < 2; ++dt)
#pragma unroll
      for (int T = 0; T < 2; ++T)
#pragma unroll
        for (int kc = 0; kc < 2; ++kc)
          acc[dt] = __builtin_amdgcn_mfma_f32_32x32x16_bf16(va[dt][T * 2 + kc], pfrag[T][kc], acc[dt], 0, 0, 0);
    __builtin_amdgcn_s_setprio(0);

    if (it < 31) {
#pragma unroll
      for (int pp = 0; pp < 2; ++pp) {
        *(short8*)(&Kt[cur ^ 1][(pp * 32 + sr) * LDK + sc]) = kn[pp];
        *(short8*)(&Vt[cur ^ 1][(pp * 32 + sr) * LDV + sc]) = vn[pp];
      }
    }
    cur ^= 1;
  }

  // --- epilogue: normalize, transpose O^T->O via per-wave LDS, coalesced store
  __syncthreads();
  lsum += __shfl_xor(lsum, 32, 64);
  float inv = 1.0f / lsum;
  short* ot = (short*)&Kt[0][0] + w * (32 * 72);
#pragma unroll
  for (int dt = 0; dt < 2; ++dt)
#pragma unroll
    for (int rq = 0; rq < 4; ++rq) {
      s4v o;
#pragma unroll
      for (int j = 0; j < 4; ++j) o[j] = f2bf(acc[dt][rq * 4 + j] * inv);
      *(s4v*)(ot + l5 * 72 + dt * 32 + rq * 8 + hi * 4) = o;
    }
  __syncthreads();
#pragma unroll
  for (int pp = 0; pp < 4; ++pp) {
    int rr = pp * 8 + (lane >> 3);
    int c8b = (lane & 7) * 8;
    short8 v = *(const short8*)(ot + rr * 72 + c8b);
    int qg = b * L_ + l0 + w * 32 + rr;
    *(short8*)(Ow + ((size_t)qg * H_ + h) * D_ + c8b) = v;
  }
}

// ---------------- Kernel 5: output projection + residual, coalesced stores -----
// Epilogue now transposes the 128x128 output tile through LDS so global stores
// are float4 runs along L (old path: 4B words scattered 8KB apart).
__global__ __launch_bounds__(256) void k_gemm_out(
    const short* __restrict__ Ow, const short* __restrict__ Wot,
    const float* __restrict__ bo, const short* __restrict__ qn,
    float* __restrict__ out) {
  int m0 = blockIdx.x * 128, n0 = blockIdx.y * 128;
  __shared__ alignas(16) char SMEMRAW[64 * 132 * 4];   // 33.8 KB: staging | Tt
  short* As = (short*)SMEMRAW;
  short* Bs = As + 128 * 64;
  float* Tt = (float*)SMEMRAW;                          // 64 x 132 f32
  int t = threadIdx.x, lane = t & 63, w = t >> 6;
  int wm = w & 1, wn = w >> 1;
  int g0 = w * 8 + (lane >> 3);
  int gc = SW8(lane);

  f32x4 zero4 = {0.f, 0.f, 0.f, 0.f};
  f32x4 acc[4][4];
  for (int i = 0; i < 4; ++i) for (int j = 0; j < 4; ++j) acc[i][j] = zero4;

  for (int k0 = 0; k0 < C_; k0 += 64) {
    __syncthreads();
#pragma unroll
    for (int i = 0; i < 4; ++i) {
      int row = i * 32 + g0;
      gload16(Ow  + (size_t)(m0 + row) * C_ + k0 + gc, As + (i * 4 + w) * 512);
      gload16(Wot + (size_t)(n0 + row) * C_ + k0 + gc, Bs + (i * 4 + w) * 512);
    }
    __syncthreads();
#pragma unroll
    for (int kk = 0; kk < 2; ++kk) {
      short8 a[4], bf[4];
#pragma unroll
      for (int i = 0; i < 4; ++i) {
        int row = wm * 64 + i * 16 + (lane & 15);
        a[i] = *(const short8*)(As + row * 64 + (((kk * 4 + (lane >> 4)) ^ (row & 7)) << 3));
      }
#pragma unroll
      for (int i = 0; i < 4; ++i) {
        int row = wn * 64 + i * 16 + (lane & 15);
        bf[i] = *(const short8*)(Bs + row * 64 + (((kk * 4 + (lane >> 4)) ^ (row & 7)) << 3));
      }
#pragma unroll
      for (int i = 0; i < 4; ++i)
#pragma unroll
        for (int j = 0; j < 4; ++j)
          acc[i][j] = __builtin_amdgcn_mfma_f32_16x16x32_bf16(a[i], bf[j], acc[i][j], 0, 0, 0);
    }
  }

  // fold bias + residual into acc (qn reads are tile-local, L1/L2-cached)
  for (int i = 0; i < 4; ++i)
    for (int j = 0; j < 4; ++j) {
      int colg = n0 + wn * 64 + j * 16 + (lane & 15);
      float bia = bo[colg];
      for (int r = 0; r < 4; ++r) {
        int rowg = m0 + wm * 64 + i * 16 + (lane >> 4) * 4 + r;
        acc[i][j][r] += bia + bf2f(qn[(size_t)rowg * C_ + colg]);
      }
    }

  // 2-pass LDS transpose; stores along L are float4-coalesced
  int bb = m0 >> 11, lb = m0 & (L_ - 1);
#pragma unroll
  for (int pass = 0; pass < 2; ++pass) {
    __syncthreads();
    if (wn == pass) {
#pragma unroll
      for (int i = 0; i < 4; ++i)
#pragma unroll
        for (int j = 0; j < 4; ++j) {
          int cl = j * 16 + (lane & 15);                 // 0..63
          int ll = wm * 64 + i * 16 + (lane >> 4) * 4;   // 0..124
          float4 v = make_float4(acc[i][j][0], acc[i][j][1], acc[i][j][2], acc[i][j][3]);
          *(float4*)&Tt[cl * 132 + ll] = v;
        }
    }
    __syncthreads();
#pragma unroll
    for (int p = 0; p < 8; ++p) {
      int u = p * 256 + t;
      int c  = u >> 5;             // 0..63
      int l4 = (u & 31) * 4;       // 0..124
      float4 v = *(float4*)&Tt[c * 132 + l4];
      int colg = n0 + pass * 64 + c;
      *(float4*)(out + ((size_t)bb * C_ + colg) * L_ + lb + l4) = v;
    }
  }
}

extern "C" void kernel_launch(void* const* d_in, const int* in_sizes, int n_in,
                              void* d_out, int out_size, void* d_ws, size_t ws_size,
                              hipStream_t stream) {
  const float* query     = (const float*)d_in[0];
  const float* key_value = (const float*)d_in[1];
  const float* pos       = (const float*)d_in[2];
  const float* qg        = (const float*)d_in[3];
  const float* qb        = (const float*)d_in[4];
  const float* kg        = (const float*)d_in[5];
  const float* kb        = (const float*)d_in[6];
  const float* Wq        = (const float*)d_in[7];
  const float* bq        = (const float*)d_in[8];
  const float* Wk        = (const float*)d_in[9];
  const float* bk        = (const float*)d_in[10];
  const float* Wv        = (const float*)d_in[11];
  const float* bv        = (const float*)d_in[12];
  const float* Wo        = (const float*)d_in[13];
  const float* bo        = (const float*)d_in[14];
  float* out = (float*)d_out;

  char* ws = (char*)d_ws;
  const size_t SZ = (size_t)B_ * L_ * C_ * 2;   // 8 MB per bf16 (B,L,C) buffer
  short* qn  = (short*)(ws + 0 * SZ);
  short* kvn = (short*)(ws + 1 * SZ);
  short* Qw  = (short*)(ws + 2 * SZ);
  short* Kw  = (short*)(ws + 3 * SZ);
  short* Vtg = (short*)(ws + 4 * SZ);           // V^T [b][h][d][l] (written by gemm z=2)
  short* Ow  = (short*)(ws + 5 * SZ);
  short* Wt  = (short*)(ws + 6 * SZ);           // 4 x 512x512 bf16 = 2 MB

  k_pre<<<dim3(1536), 256, 0, stream>>>(query, key_value, pos, qg, qb, kg, kb,
                                        Wq, Wk, Wv, Wo, qn, kvn, Wt);
  k_gemm_qkv<<<dim3(8192 / 128, C_ / 128, 3), 256, 0, stream>>>(qn, kvn, Wt, bq, bk, bv, Qw, Kw, Vtg);
  k_attn<<<dim3(L_ / 128, H_, B_), 256, 0, stream>>>(Qw, Kw, Vtg, Ow);
  k_gemm_out<<<dim3(8192 / 128, C_ / 128, 1), 256, 0, stream>>>(Ow, Wt + (size_t)3 * C_ * C_, bo, qn, out);
}

// Round 10
// 194.619 us; speedup vs baseline: 1.3500x; 1.0102x over previous
//
#include <hip/hip_runtime.h>
#include <hip/hip_bf16.h>

#define B_ 4
#define C_ 512
#define L_ 2048
#define H_ 8
#define D_ 64
#define EPS_ 1e-5f

using short8 = __attribute__((ext_vector_type(8))) short;
using s4v    = __attribute__((ext_vector_type(4))) short;
using f32x4  = __attribute__((ext_vector_type(4))) float;
using f32x16 = __attribute__((ext_vector_type(16))) float;
using uint2v = __attribute__((ext_vector_type(2))) unsigned int;

static __device__ __forceinline__ short f2bf(float f) {
  __hip_bfloat16 h = __float2bfloat16(f);
  return __builtin_bit_cast(short, h);
}
static __device__ __forceinline__ float bf2f(short s) {
  return __bfloat162float(__builtin_bit_cast(__hip_bfloat16, s));
}
static __device__ __forceinline__ unsigned cvtpk(float lo, float hi) {
  unsigned d;
  asm("v_cvt_pk_bf16_f32 %0, %1, %2" : "=v"(d) : "v"(lo), "v"(hi));
  return d;
}
static __device__ __forceinline__ void pl32swap(unsigned& a, unsigned& b) {
  uint2v r = __builtin_amdgcn_permlane32_swap(a, b, false, false);
  a = r[0]; b = r[1];
}
static __device__ __forceinline__ short8 mk8(unsigned w0, unsigned w1, unsigned w2, unsigned w3) {
  union { unsigned u[4]; short8 s; } u;
  u.u[0] = w0; u.u[1] = w1; u.u[2] = w2; u.u[3] = w3;
  return u.s;
}
static __device__ __forceinline__ void gload16(const void* g, void* l) {
  __builtin_amdgcn_global_load_lds(
      (const __attribute__((address_space(1))) unsigned int*)g,
      (__attribute__((address_space(3))) unsigned int*)l, 16, 0, 0);
}
#define SW8(l) (((((l) & 7) ^ (((l) >> 3) & 7))) << 3)

// ---------------- Kernel A: fused {weights fp32->bf16 transpose} + {prep/LN} ---
__global__ __launch_bounds__(256) void k_pre(
    const float* __restrict__ query, const float* __restrict__ kv,
    const float* __restrict__ pos,
    const float* __restrict__ qg, const float* __restrict__ qb,
    const float* __restrict__ kg, const float* __restrict__ kb,
    const float* __restrict__ Wq, const float* __restrict__ Wk,
    const float* __restrict__ Wv, const float* __restrict__ Wo,
    short* __restrict__ qn, short* __restrict__ kvn, short* __restrict__ Wt) {
  __shared__ float SM[32 * 516 + 64];
  int bid = blockIdx.x, t = threadIdx.x;

  if (bid >= 512) {
    int cid = bid - 512;
    int m = cid >> 8, k0 = ((cid >> 4) & 15) * 32, n0 = (cid & 15) * 32;
    const float* W = (m == 0) ? Wq : (m == 1) ? Wk : (m == 2) ? Wv : Wo;
    float* T = SM;
    {
      int kl = t >> 3, n4 = (t & 7) * 4;
      float4 v = *(const float4*)(W + (size_t)(k0 + kl) * C_ + n0 + n4);
      T[kl * 33 + n4] = v.x; T[kl * 33 + n4 + 1] = v.y;
      T[kl * 33 + n4 + 2] = v.z; T[kl * 33 + n4 + 3] = v.w;
    }
    __syncthreads();
    {
      int nl = t >> 3, k4 = (t & 7) * 4;
      s4v o;
#pragma unroll
      for (int j = 0; j < 4; ++j) o[j] = f2bf(T[(k4 + j) * 33 + nl]);
      *(s4v*)(Wt + (size_t)(m * C_ + n0 + nl) * C_ + k0 + k4) = o;
    }
    return;
  }

  int l0 = (bid & 63) * 32;
  int b  = (bid >> 6) & 3;
  int z  = bid >> 8;
  const float* src = z ? kv : query;
  const float* g   = z ? kg : qg;
  const float* be  = z ? kb : qb;
  short* dst       = z ? kvn : qn;

  float* T = SM;
  float* mu_s = SM + 32 * 516;
  float* rs_s = mu_s + 32;

#pragma unroll
  for (int i = 0; i < 16; ++i) {
    int c  = i * 32 + (t >> 3);
    int lg = (t & 7) * 4;
    float4 v = *(const float4*)(src + (size_t)(b * C_ + c) * L_ + l0 + lg);
    T[lg * 516 + c] = v.x; T[(lg + 1) * 516 + c] = v.y;
    T[(lg + 2) * 516 + c] = v.z; T[(lg + 3) * 516 + c] = v.w;
  }
  __syncthreads();
  {
    int row = t >> 3, j = t & 7;
    const float* prow = pos + (size_t)(l0 + row) * C_;
    float s1 = 0.f, s2 = 0.f;
#pragma unroll
    for (int k = 0; k < 16; ++k) {
      int c4 = j * 4 + k * 32;
      float4 v = *(const float4*)&T[row * 516 + c4];
      float4 p = *(const float4*)(prow + c4);
      v.x += p.x; v.y += p.y; v.z += p.z; v.w += p.w;
      *(float4*)&T[row * 516 + c4] = v;
      s1 += v.x + v.y + v.z + v.w;
      s2 += v.x * v.x + v.y * v.y + v.z * v.z + v.w * v.w;
    }
    s1 += __shfl_xor(s1, 1, 64); s2 += __shfl_xor(s2, 1, 64);
    s1 += __shfl_xor(s1, 2, 64); s2 += __shfl_xor(s2, 2, 64);
    s1 += __shfl_xor(s1, 4, 64); s2 += __shfl_xor(s2, 4, 64);
    if (j == 0) {
      float mu  = s1 * (1.0f / C_);
      float var = s2 * (1.0f / C_) - mu * mu;
      mu_s[row] = mu;
      rs_s[row] = rsqrtf(var + EPS_);
    }
  }
  __syncthreads();
#pragma unroll
  for (int i = 0; i < 8; ++i) {
    int row = i * 4 + (t >> 6);
    int c   = (t & 63) * 8;
    float mu = mu_s[row], rs = rs_s[row];
    short8 o;
#pragma unroll
    for (int jj = 0; jj < 8; ++jj) {
      float v = (T[row * 516 + c + jj] - mu) * rs * g[c + jj] + be[c + jj];
      o[jj] = f2bf(v);
    }
    *(short8*)(dst + (size_t)(b * L_ + l0 + row) * C_ + c) = o;
  }
}

// ---------------- Kernel 3: fused QKV GEMM; coalesced epilogues everywhere -----
// z<2: LDS-transpose epilogue -> short8 row-runs to Y (was 64 scalar 2B stores).
// z==2: transposed epilogue -> Vtg[b][h][d][l] (as before).
__global__ __launch_bounds__(256) void k_gemm_qkv(
    const short* __restrict__ qn, const short* __restrict__ kvn,
    const short* __restrict__ Wt,
    const float* __restrict__ bq, const float* __restrict__ bk, const float* __restrict__ bv,
    short* __restrict__ Qw, short* __restrict__ Kw, short* __restrict__ Vtg) {
  int z = blockIdx.z;
  const short* X    = z ? kvn : qn;
  const short* W    = Wt + (size_t)z * C_ * C_;
  const float* bias = (z == 0) ? bq : (z == 1) ? bk : bv;
  float sc          = (z == 0) ? 0.18033688011112042f : 1.0f;  // 0.125*log2(e)

  int m0 = blockIdx.x * 128, n0 = blockIdx.y * 128;
  __shared__ alignas(16) short SMEM[128 * 64 * 2];   // As | Bs ; reused as Tt
  short* As = SMEM;
  short* Bs = SMEM + 128 * 64;
  int t = threadIdx.x, lane = t & 63, w = t >> 6;
  int wm = w & 1, wn = w >> 1;
  int g0 = w * 8 + (lane >> 3);
  int gc = SW8(lane);

  f32x4 zero4 = {0.f, 0.f, 0.f, 0.f};
  f32x4 acc[4][4];
  for (int i = 0; i < 4; ++i) for (int j = 0; j < 4; ++j) acc[i][j] = zero4;

  for (int k0 = 0; k0 < C_; k0 += 64) {
    __syncthreads();
#pragma unroll
    for (int i = 0; i < 4; ++i) {
      int row = i * 32 + g0;
      gload16(X + (size_t)(m0 + row) * C_ + k0 + gc, As + (i * 4 + w) * 512);
      gload16(W + (size_t)(n0 + row) * C_ + k0 + gc, Bs + (i * 4 + w) * 512);
    }
    __syncthreads();
#pragma unroll
    for (int kk = 0; kk < 2; ++kk) {
      short8 a[4], bf[4];
#pragma unroll
      for (int i = 0; i < 4; ++i) {
        int row = wm * 64 + i * 16 + (lane & 15);
        a[i] = *(const short8*)(As + row * 64 + (((kk * 4 + (lane >> 4)) ^ (row & 7)) << 3));
      }
#pragma unroll
      for (int i = 0; i < 4; ++i) {
        int row = wn * 64 + i * 16 + (lane & 15);
        bf[i] = *(const short8*)(Bs + row * 64 + (((kk * 4 + (lane >> 4)) ^ (row & 7)) << 3));
      }
#pragma unroll
      for (int i = 0; i < 4; ++i)
#pragma unroll
        for (int j = 0; j < 4; ++j)
          acc[i][j] = __builtin_amdgcn_mfma_f32_16x16x32_bf16(a[i], bf[j], acc[i][j], 0, 0, 0);
    }
  }

  if (z < 2) {
    // ---- LDS-transpose epilogue: Tt[row 0..127][col 0..63 +2pad] shorts ------
    short* Y  = (z == 0) ? Qw : Kw;
    short* Tt = SMEM;   // 128 x 66 shorts = 16.9 KB
#pragma unroll
    for (int pass = 0; pass < 2; ++pass) {
      __syncthreads();
      if (wn == pass) {
#pragma unroll
        for (int i = 0; i < 4; ++i)
#pragma unroll
          for (int j = 0; j < 4; ++j) {
            int cl  = j * 16 + (lane & 15);
            float bia = bias[n0 + pass * 64 + cl];
            int r0  = wm * 64 + i * 16 + (lane >> 4) * 4;
#pragma unroll
            for (int r = 0; r < 4; ++r)
              Tt[(r0 + r) * 66 + cl] = f2bf((acc[i][j][r] + bia) * sc);
          }
      }
      __syncthreads();
#pragma unroll
      for (int p = 0; p < 4; ++p) {
        int u = p * 256 + t;
        int row = u >> 3, c8 = (u & 7) * 8;
        short8 v = *(const short8*)(Tt + row * 66 + c8);
        *(short8*)(Y + (size_t)(m0 + row) * C_ + n0 + pass * 64 + c8) = v;
      }
    }
    return;
  }

  // ---- z == 2: transposed epilogue -> Vtg[b][h][d][l], via LDS (2 passes) ----
  short* Tt = SMEM;   // 64 cols x 136 (128 l + pad) shorts
  int bb = m0 >> 11, lb = m0 & (L_ - 1);
#pragma unroll
  for (int pass = 0; pass < 2; ++pass) {
    __syncthreads();
    if (wn == pass) {
#pragma unroll
      for (int i = 0; i < 4; ++i)
#pragma unroll
        for (int j = 0; j < 4; ++j) {
          int cl = j * 16 + (lane & 15);
          float bia = bias[n0 + pass * 64 + cl];
          int ll = wm * 64 + i * 16 + (lane >> 4) * 4;
          s4v o;
#pragma unroll
          for (int r = 0; r < 4; ++r) o[r] = f2bf(acc[i][j][r] + bia);
          *(s4v*)(Tt + cl * 136 + ll) = o;
        }
    }
    __syncthreads();
#pragma unroll
    for (int p = 0; p < 4; ++p) {
      int u = p * 256 + t;
      int c = u >> 4;
      int l8 = (u & 15) * 8;
      int colg = n0 + pass * 64 + c;
      int hh = colg >> 6, dd = colg & 63;
      short8 v = *(short8*)(Tt + c * 136 + l8);
      *(short8*)(Vtg + ((size_t)(bb * H_ + hh) * D_ + dd) * L_ + lb + l8) = v;
    }
  }
}

// ---------------- Kernel 4: attention (round-7 structure, best measured) -------
#define LDK 72
#define LDV 72
__global__ __launch_bounds__(256, 2) void k_attn(
    const short* __restrict__ Qw, const short* __restrict__ Kw,
    const short* __restrict__ Vtg, short* __restrict__ Ow) {
  int l0 = blockIdx.x * 128;
  int h  = blockIdx.y;
  int b  = blockIdx.z;
  __shared__ alignas(16) short Kt[2][64 * LDK];
  __shared__ alignas(16) short Vt[2][64 * LDV];
  int t = threadIdx.x, lane = t & 63, w = t >> 6;
  int l5 = lane & 31, hi = lane >> 5;

  short8 qf[4];
  {
    int qrow = b * L_ + l0 + w * 32 + l5;
    const short* qp = Qw + ((size_t)qrow * H_ + h) * D_ + hi * 8;
#pragma unroll
    for (int kc = 0; kc < 4; ++kc) qf[kc] = *(const short8*)(qp + kc * 16);
  }

  f32x16 acc[2];
#pragma unroll
  for (int dt = 0; dt < 2; ++dt)
#pragma unroll
    for (int r = 0; r < 16; ++r) acc[dt][r] = 0.f;
  float lsum = 0.f;

  const short* Kbase = Kw + (size_t)(b * L_) * C_ + h * D_;
  const short* Vbase = Vtg + (size_t)(b * H_ + h) * D_ * L_;

  int sr = t >> 3, sc = (t & 7) * 8;

  {
    short8 kr[2], vr[2];
#pragma unroll
    for (int p = 0; p < 2; ++p) {
      kr[p] = *(const short8*)(Kbase + (size_t)(p * 32 + sr) * C_ + sc);
      vr[p] = *(const short8*)(Vbase + (size_t)(p * 32 + sr) * L_ + sc);
    }
#pragma unroll
    for (int p = 0; p < 2; ++p) {
      *(short8*)(&Kt[0][(p * 32 + sr) * LDK + sc]) = kr[p];
      *(short8*)(&Vt[0][(p * 32 + sr) * LDV + sc]) = vr[p];
    }
  }

  int cur = 0;
  for (int it = 0; it < 32; ++it) {
    __syncthreads();
    short8 kn[2], vn[2];
    if (it < 31) {
      int lr0 = (it + 1) * 64;
#pragma unroll
      for (int p = 0; p < 2; ++p) {
        kn[p] = *(const short8*)(Kbase + (size_t)(lr0 + p * 32 + sr) * C_ + sc);
        vn[p] = *(const short8*)(Vbase + (size_t)(p * 32 + sr) * L_ + lr0 + sc);
      }
    }
    const short* KT = &Kt[cur][0];
    const short* VT = &Vt[cur][0];

    f32x16 st[2];
#pragma unroll
    for (int T = 0; T < 2; ++T)
#pragma unroll
      for (int r = 0; r < 16; ++r) st[T][r] = 0.f;
    __builtin_amdgcn_s_setprio(1);
#pragma unroll
    for (int T = 0; T < 2; ++T)
#pragma unroll
      for (int kc = 0; kc < 4; ++kc) {
        short8 kf = *(const short8*)(KT + (T * 32 + l5) * LDK + kc * 16 + hi * 8);
        st[T] = __builtin_amdgcn_mfma_f32_32x32x16_bf16(kf, qf[kc], st[T], 0, 0, 0);
      }
    __builtin_amdgcn_s_setprio(0);

    short8 va[2][4];
#pragma unroll
    for (int dt = 0; dt < 2; ++dt)
#pragma unroll
      for (int kc = 0; kc < 4; ++kc)
        va[dt][kc] = *(const short8*)(VT + (dt * 32 + l5) * LDV + kc * 16 + hi * 8);

    short8 pfrag[2][2];
#pragma unroll
    for (int T = 0; T < 2; ++T) {
      float ps[16];
#pragma unroll
      for (int r = 0; r < 16; ++r) {
        float pv = __builtin_amdgcn_exp2f(st[T][r]);
        lsum += pv;
        ps[r] = pv;
      }
      unsigned d0 = cvtpk(ps[0], ps[1]),   d1 = cvtpk(ps[2], ps[3]);
      unsigned d2 = cvtpk(ps[4], ps[5]),   d3 = cvtpk(ps[6], ps[7]);
      pl32swap(d0, d2); pl32swap(d1, d3);
      pfrag[T][0] = mk8(d0, d1, d2, d3);
      unsigned e0 = cvtpk(ps[8], ps[9]),   e1 = cvtpk(ps[10], ps[11]);
      unsigned e2 = cvtpk(ps[12], ps[13]), e3 = cvtpk(ps[14], ps[15]);
      pl32swap(e0, e2); pl32swap(e1, e3);
      pfrag[T][1] = mk8(e0, e1, e2, e3);
    }

    __builtin_amdgcn_s_setprio(1);
#pragma unroll
    for (int dt = 0; dt < 2; ++dt)
#pragma unroll
      for (int T = 0; T < 2; ++T)
#pragma unroll
        for (int kc = 0; kc < 2; ++kc)
          acc[dt] = __builtin_amdgcn_mfma_f32_32x32x16_bf16(va[dt][T * 2 + kc], pfrag[T][kc], acc[dt], 0, 0, 0);
    __builtin_amdgcn_s_setprio(0);

    if (it < 31) {
#pragma unroll
      for (int p = 0; p < 2; ++p) {
        *(short8*)(&Kt[cur ^ 1][(p * 32 + sr) * LDK + sc]) = kn[p];
        *(short8*)(&Vt[cur ^ 1][(p * 32 + sr) * LDV + sc]) = vn[p];
      }
    }
    cur ^= 1;
  }

  __syncthreads();
  lsum += __shfl_xor(lsum, 32, 64);
  float inv = 1.0f / lsum;
  short* ot = (short*)&Kt[0][0] + w * (32 * 72);
#pragma unroll
  for (int dt = 0; dt < 2; ++dt)
#pragma unroll
    for (int rq = 0; rq < 4; ++rq) {
      s4v o;
#pragma unroll
      for (int j = 0; j < 4; ++j) o[j] = f2bf(acc[dt][rq * 4 + j] * inv);
      *(s4v*)(ot + l5 * 72 + dt * 32 + rq * 8 + hi * 4) = o;
    }
  __syncthreads();
#pragma unroll
  for (int p = 0; p < 4; ++p) {
    int rr = p * 8 + (lane >> 3);
    int c8b = (lane & 7) * 8;
    short8 v = *(const short8*)(ot + rr * 72 + c8b);
    int qg = b * L_ + l0 + w * 32 + rr;
    *(short8*)(Ow + ((size_t)qg * H_ + h) * D_ + c8b) = v;
  }
}

// ---------------- Kernel 5: output projection, 64x128 tiles (2 blocks/CU) ------
__global__ __launch_bounds__(256) void k_gemm_out(
    const short* __restrict__ Ow, const short* __restrict__ Wot,
    const float* __restrict__ bo, const short* __restrict__ qn,
    float* __restrict__ out) {
  int m0 = blockIdx.x * 64, n0 = blockIdx.y * 128;
  __shared__ alignas(16) char SMEMRAW[24576];   // As 8K | Bs 16K ; Tt 17.4K
  short* As = (short*)SMEMRAW;
  short* Bs = As + 64 * 64;
  float* Tt = (float*)SMEMRAW;                  // 64 x 68 f32
  int t = threadIdx.x, lane = t & 63, w = t >> 6;
  int wm = w & 1, wn = w >> 1;
  int g0 = w * 8 + (lane >> 3);
  int gc = SW8(lane);

  f32x4 zero4 = {0.f, 0.f, 0.f, 0.f};
  f32x4 acc[2][4];
  for (int i = 0; i < 2; ++i) for (int j = 0; j < 4; ++j) acc[i][j] = zero4;

  for (int k0 = 0; k0 < C_; k0 += 64) {
    __syncthreads();
#pragma unroll
    for (int j = 0; j < 2; ++j) {
      int row = j * 32 + g0;
      gload16(Ow + (size_t)(m0 + row) * C_ + k0 + gc, As + (j * 4 + w) * 512);
    }
#pragma unroll
    for (int i = 0; i < 4; ++i) {
      int row = i * 32 + g0;
      gload16(Wot + (size_t)(n0 + row) * C_ + k0 + gc, Bs + (i * 4 + w) * 512);
    }
    __syncthreads();
#pragma unroll
    for (int kk = 0; kk < 2; ++kk) {
      short8 a[2], bf[4];
#pragma unroll
      for (int i = 0; i < 2; ++i) {
        int row = wm * 32 + i * 16 + (lane & 15);
        a[i] = *(const short8*)(As + row * 64 + (((kk * 4 + (lane >> 4)) ^ (row & 7)) << 3));
      }
#pragma unroll
      for (int i = 0; i < 4; ++i) {
        int row = wn * 64 + i * 16 + (lane & 15);
        bf[i] = *(const short8*)(Bs + row * 64 + (((kk * 4 + (lane >> 4)) ^ (row & 7)) << 3));
      }
#pragma unroll
      for (int i = 0; i < 2; ++i)
#pragma unroll
        for (int j = 0; j < 4; ++j)
          acc[i][j] = __builtin_amdgcn_mfma_f32_16x16x32_bf16(a[i], bf[j], acc[i][j], 0, 0, 0);
    }
  }

  // fold bias + residual
  for (int i = 0; i < 2; ++i)
    for (int j = 0; j < 4; ++j) {
      int colg = n0 + wn * 64 + j * 16 + (lane & 15);
      float bia = bo[colg];
      for (int r = 0; r < 4; ++r) {
        int rowg = m0 + wm * 32 + i * 16 + (lane >> 4) * 4 + r;
        acc[i][j][r] += bia + bf2f(qn[(size_t)rowg * C_ + colg]);
      }
    }

  // 2-pass LDS transpose; float4 stores along L
  int bb = m0 >> 11, lb = m0 & (L_ - 1);
#pragma unroll
  for (int pass = 0; pass < 2; ++pass) {
    __syncthreads();
    if (wn == pass) {
#pragma unroll
      for (int i = 0; i < 2; ++i)
#pragma unroll
        for (int j = 0; j < 4; ++j) {
          int cl = j * 16 + (lane & 15);                 // 0..63
          int ll = wm * 32 + i * 16 + (lane >> 4) * 4;   // 0..60
          float4 v = make_float4(acc[i][j][0], acc[i][j][1], acc[i][j][2], acc[i][j][3]);
          *(float4*)&Tt[cl * 68 + ll] = v;
        }
    }
    __syncthreads();
#pragma unroll
    for (int p = 0; p < 4; ++p) {
      int u = p * 256 + t;
      int c  = u >> 4;             // 0..63
      int l4 = (u & 15) * 4;       // 0..60
      float4 v = *(float4*)&Tt[c * 68 + l4];
      int colg = n0 + pass * 64 + c;
      *(float4*)(out + ((size_t)bb * C_ + colg) * L_ + lb + l4) = v;
    }
  }
}

extern "C" void kernel_launch(void* const* d_in, const int* in_sizes, int n_in,
                              void* d_out, int out_size, void* d_ws, size_t ws_size,
                              hipStream_t stream) {
  const float* query     = (const float*)d_in[0];
  const float* key_value = (const float*)d_in[1];
  const float* pos       = (const float*)d_in[2];
  const float* qg        = (const float*)d_in[3];
  const float* qb        = (const float*)d_in[4];
  const float* kg        = (const float*)d_in[5];
  const float* kb        = (const float*)d_in[6];
  const float* Wq        = (const float*)d_in[7];
  const float* bq        = (const float*)d_in[8];
  const float* Wk        = (const float*)d_in[9];
  const float* bk        = (const float*)d_in[10];
  const float* Wv        = (const float*)d_in[11];
  const float* bv        = (const float*)d_in[12];
  const float* Wo        = (const float*)d_in[13];
  const float* bo        = (const float*)d_in[14];
  float* out = (float*)d_out;

  char* ws = (char*)d_ws;
  const size_t SZ = (size_t)B_ * L_ * C_ * 2;   // 8 MB per bf16 (B,L,C) buffer
  short* qn  = (short*)(ws + 0 * SZ);
  short* kvn = (short*)(ws + 1 * SZ);
  short* Qw  = (short*)(ws + 2 * SZ);
  short* Kw  = (short*)(ws + 3 * SZ);
  short* Vtg = (short*)(ws + 4 * SZ);           // V^T [b][h][d][l] (written by gemm z=2)
  short* Ow  = (short*)(ws + 5 * SZ);
  short* Wt  = (short*)(ws + 6 * SZ);           // 4 x 512x512 bf16 = 2 MB

  k_pre<<<dim3(1536), 256, 0, stream>>>(query, key_value, pos, qg, qb, kg, kb,
                                        Wq, Wk, Wv, Wo, qn, kvn, Wt);
  k_gemm_qkv<<<dim3(8192 / 128, C_ / 128, 3), 256, 0, stream>>>(qn, kvn, Wt, bq, bk, bv, Qw, Kw, Vtg);
  k_attn<<<dim3(L_ / 128, H_, B_), 256, 0, stream>>>(Qw, Kw, Vtg, Ow);
  k_gemm_out<<<dim3(8192 / 64, C_ / 128, 1), 256, 0, stream>>>(Ow, Wt + (size_t)3 * C_ * C_, bo, qn, out);
}

// Round 13
// 190.658 us; speedup vs baseline: 1.3781x; 1.0208x over previous
//
#include <hip/hip_runtime.h>
#include <hip/hip_bf16.h>

#define B_ 4
#define C_ 512
#define L_ 2048
#define H_ 8
#define D_ 64
#define EPS_ 1e-5f

using short8 = __attribute__((ext_vector_type(8))) short;
using s4v    = __attribute__((ext_vector_type(4))) short;
using f32x4  = __attribute__((ext_vector_type(4))) float;
using f32x16 = __attribute__((ext_vector_type(16))) float;
using uint2v = __attribute__((ext_vector_type(2))) unsigned int;

static __device__ __forceinline__ short f2bf(float f) {
  __hip_bfloat16 h = __float2bfloat16(f);
  return __builtin_bit_cast(short, h);
}
static __device__ __forceinline__ float bf2f(short s) {
  return __bfloat162float(__builtin_bit_cast(__hip_bfloat16, s));
}
static __device__ __forceinline__ unsigned cvtpk(float lo, float hi) {
  unsigned d;
  asm("v_cvt_pk_bf16_f32 %0, %1, %2" : "=v"(d) : "v"(lo), "v"(hi));
  return d;
}
static __device__ __forceinline__ void pl32swap(unsigned& a, unsigned& b) {
  uint2v r = __builtin_amdgcn_permlane32_swap(a, b, false, false);
  a = r[0]; b = r[1];
}
static __device__ __forceinline__ short8 mk8(unsigned w0, unsigned w1, unsigned w2, unsigned w3) {
  union { unsigned u[4]; short8 s; } u;
  u.u[0] = w0; u.u[1] = w1; u.u[2] = w2; u.u[3] = w3;
  return u.s;
}
static __device__ __forceinline__ void gload16(const void* g, void* l) {
  __builtin_amdgcn_global_load_lds(
      (const __attribute__((address_space(1))) unsigned int*)g,
      (__attribute__((address_space(3))) unsigned int*)l, 16, 0, 0);
}
#define SW8(l) (((((l) & 7) ^ (((l) >> 3) & 7))) << 3)

// ---------------- Kernel A: fused {weights fp32->bf16 transpose} + {prep/LN} ---
__global__ __launch_bounds__(256) void k_pre(
    const float* __restrict__ query, const float* __restrict__ kv,
    const float* __restrict__ pos,
    const float* __restrict__ qg, const float* __restrict__ qb,
    const float* __restrict__ kg, const float* __restrict__ kb,
    const float* __restrict__ Wq, const float* __restrict__ Wk,
    const float* __restrict__ Wv, const float* __restrict__ Wo,
    short* __restrict__ qn, short* __restrict__ kvn, short* __restrict__ Wt) {
  __shared__ float SM[32 * 516 + 64];
  int bid = blockIdx.x, t = threadIdx.x;

  if (bid >= 512) {
    int cid = bid - 512;
    int m = cid >> 8, k0 = ((cid >> 4) & 15) * 32, n0 = (cid & 15) * 32;
    const float* W = (m == 0) ? Wq : (m == 1) ? Wk : (m == 2) ? Wv : Wo;
    float* T = SM;
    {
      int kl = t >> 3, n4 = (t & 7) * 4;
      float4 v = *(const float4*)(W + (size_t)(k0 + kl) * C_ + n0 + n4);
      T[kl * 33 + n4] = v.x; T[kl * 33 + n4 + 1] = v.y;
      T[kl * 33 + n4 + 2] = v.z; T[kl * 33 + n4 + 3] = v.w;
    }
    __syncthreads();
    {
      int nl = t >> 3, k4 = (t & 7) * 4;
      s4v o;
#pragma unroll
      for (int j = 0; j < 4; ++j) o[j] = f2bf(T[(k4 + j) * 33 + nl]);
      *(s4v*)(Wt + (size_t)(m * C_ + n0 + nl) * C_ + k0 + k4) = o;
    }
    return;
  }

  int l0 = (bid & 63) * 32;
  int b  = (bid >> 6) & 3;
  int z  = bid >> 8;
  const float* src = z ? kv : query;
  const float* g   = z ? kg : qg;
  const float* be  = z ? kb : qb;
  short* dst       = z ? kvn : qn;

  float* T = SM;
  float* mu_s = SM + 32 * 516;
  float* rs_s = mu_s + 32;

#pragma unroll
  for (int i = 0; i < 16; ++i) {
    int c  = i * 32 + (t >> 3);
    int lg = (t & 7) * 4;
    float4 v = *(const float4*)(src + (size_t)(b * C_ + c) * L_ + l0 + lg);
    T[lg * 516 + c] = v.x; T[(lg + 1) * 516 + c] = v.y;
    T[(lg + 2) * 516 + c] = v.z; T[(lg + 3) * 516 + c] = v.w;
  }
  __syncthreads();
  {
    int row = t >> 3, j = t & 7;
    const float* prow = pos + (size_t)(l0 + row) * C_;
    float s1 = 0.f, s2 = 0.f;
#pragma unroll
    for (int k = 0; k < 16; ++k) {
      int c4 = j * 4 + k * 32;
      float4 v = *(const float4*)&T[row * 516 + c4];
      float4 p = *(const float4*)(prow + c4);
      v.x += p.x; v.y += p.y; v.z += p.z; v.w += p.w;
      *(float4*)&T[row * 516 + c4] = v;
      s1 += v.x + v.y + v.z + v.w;
      s2 += v.x * v.x + v.y * v.y + v.z * v.z + v.w * v.w;
    }
    s1 += __shfl_xor(s1, 1, 64); s2 += __shfl_xor(s2, 1, 64);
    s1 += __shfl_xor(s1, 2, 64); s2 += __shfl_xor(s2, 2, 64);
    s1 += __shfl_xor(s1, 4, 64); s2 += __shfl_xor(s2, 4, 64);
    if (j == 0) {
      float mu  = s1 * (1.0f / C_);
      float var = s2 * (1.0f / C_) - mu * mu;
      mu_s[row] = mu;
      rs_s[row] = rsqrtf(var + EPS_);
    }
  }
  __syncthreads();
#pragma unroll
  for (int i = 0; i < 8; ++i) {
    int row = i * 4 + (t >> 6);
    int c   = (t & 63) * 8;
    float mu = mu_s[row], rs = rs_s[row];
    short8 o;
#pragma unroll
    for (int jj = 0; jj < 8; ++jj) {
      float v = (T[row * 516 + c + jj] - mu) * rs * g[c + jj] + be[c + jj];
      o[jj] = f2bf(v);
    }
    *(short8*)(dst + (size_t)(b * L_ + l0 + row) * C_ + c) = o;
  }
}

// ---------------- Kernel 3: fused QKV GEMM; coalesced epilogues everywhere -----
// z<2: LDS-transpose epilogue -> short8 row-runs to Y (was 64 scalar 2B stores).
// z==2: transposed epilogue -> Vtg[b][h][d][l] (as before).
__global__ __launch_bounds__(256) void k_gemm_qkv(
    const short* __restrict__ qn, const short* __restrict__ kvn,
    const short* __restrict__ Wt,
    const float* __restrict__ bq, const float* __restrict__ bk, const float* __restrict__ bv,
    short* __restrict__ Qw, short* __restrict__ Kw, short* __restrict__ Vtg) {
  int z = blockIdx.z;
  const short* X    = z ? kvn : qn;
  const short* W    = Wt + (size_t)z * C_ * C_;
  const float* bias = (z == 0) ? bq : (z == 1) ? bk : bv;
  float sc          = (z == 0) ? 0.18033688011112042f : 1.0f;  // 0.125*log2(e)

  int m0 = blockIdx.x * 128, n0 = blockIdx.y * 128;
  __shared__ alignas(16) short SMEM[128 * 64 * 2];   // As | Bs ; reused as Tt
  short* As = SMEM;
  short* Bs = SMEM + 128 * 64;
  int t = threadIdx.x, lane = t & 63, w = t >> 6;
  int wm = w & 1, wn = w >> 1;
  int g0 = w * 8 + (lane >> 3);
  int gc = SW8(lane);

  f32x4 zero4 = {0.f, 0.f, 0.f, 0.f};
  f32x4 acc[4][4];
  for (int i = 0; i < 4; ++i) for (int j = 0; j < 4; ++j) acc[i][j] = zero4;

  for (int k0 = 0; k0 < C_; k0 += 64) {
    __syncthreads();
#pragma unroll
    for (int i = 0; i < 4; ++i) {
      int row = i * 32 + g0;
      gload16(X + (size_t)(m0 + row) * C_ + k0 + gc, As + (i * 4 + w) * 512);
      gload16(W + (size_t)(n0 + row) * C_ + k0 + gc, Bs + (i * 4 + w) * 512);
    }
    __syncthreads();
#pragma unroll
    for (int kk = 0; kk < 2; ++kk) {
      short8 a[4], bf[4];
#pragma unroll
      for (int i = 0; i < 4; ++i) {
        int row = wm * 64 + i * 16 + (lane & 15);
        a[i] = *(const short8*)(As + row * 64 + (((kk * 4 + (lane >> 4)) ^ (row & 7)) << 3));
      }
#pragma unroll
      for (int i = 0; i < 4; ++i) {
        int row = wn * 64 + i * 16 + (lane & 15);
        bf[i] = *(const short8*)(Bs + row * 64 + (((kk * 4 + (lane >> 4)) ^ (row & 7)) << 3));
      }
#pragma unroll
      for (int i = 0; i < 4; ++i)
#pragma unroll
        for (int j = 0; j < 4; ++j)
          acc[i][j] = __builtin_amdgcn_mfma_f32_16x16x32_bf16(a[i], bf[j], acc[i][j], 0, 0, 0);
    }
  }

  if (z < 2) {
    // ---- LDS-transpose epilogue: Tt[row 0..127][col 0..63 +2pad] shorts ------
    short* Y  = (z == 0) ? Qw : Kw;
    short* Tt = SMEM;   // 128 x 66 shorts = 16.9 KB
#pragma unroll
    for (int pass = 0; pass < 2; ++pass) {
      __syncthreads();
      if (wn == pass) {
#pragma unroll
        for (int i = 0; i < 4; ++i)
#pragma unroll
          for (int j = 0; j < 4; ++j) {
            int cl  = j * 16 + (lane & 15);
            float bia = bias[n0 + pass * 64 + cl];
            int r0  = wm * 64 + i * 16 + (lane >> 4) * 4;
#pragma unroll
            for (int r = 0; r < 4; ++r)
              Tt[(r0 + r) * 66 + cl] = f2bf((acc[i][j][r] + bia) * sc);
          }
      }
      __syncthreads();
#pragma unroll
      for (int p = 0; p < 4; ++p) {
        int u = p * 256 + t;
        int row = u >> 3, c8 = (u & 7) * 8;
        short8 v = *(const short8*)(Tt + row * 66 + c8);
        *(short8*)(Y + (size_t)(m0 + row) * C_ + n0 + pass * 64 + c8) = v;
      }
    }
    return;
  }

  // ---- z == 2: transposed epilogue -> Vtg[b][h][d][l], via LDS (2 passes) ----
  short* Tt = SMEM;   // 64 cols x 136 (128 l + pad) shorts
  int bb = m0 >> 11, lb = m0 & (L_ - 1);
#pragma unroll
  for (int pass = 0; pass < 2; ++pass) {
    __syncthreads();
    if (wn == pass) {
#pragma unroll
      for (int i = 0; i < 4; ++i)
#pragma unroll
        for (int j = 0; j < 4; ++j) {
          int cl = j * 16 + (lane & 15);
          float bia = bias[n0 + pass * 64 + cl];
          int ll = wm * 64 + i * 16 + (lane >> 4) * 4;
          s4v o;
#pragma unroll
          for (int r = 0; r < 4; ++r) o[r] = f2bf(acc[i][j][r] + bia);
          *(s4v*)(Tt + cl * 136 + ll) = o;
        }
    }
    __syncthreads();
#pragma unroll
    for (int p = 0; p < 4; ++p) {
      int u = p * 256 + t;
      int c = u >> 4;
      int l8 = (u & 15) * 8;
      int colg = n0 + pass * 64 + c;
      int hh = colg >> 6, dd = colg & 63;
      short8 v = *(short8*)(Tt + c * 136 + l8);
      *(short8*)(Vtg + ((size_t)(bb * H_ + hh) * D_ + dd) * L_ + lb + l8) = v;
    }
  }
}

// ---------------- Kernel 4: attention (round-7 structure, best measured) -------
#define LDK 72
#define LDV 72
__global__ __launch_bounds__(256, 2) void k_attn(
    const short* __restrict__ Qw, const short* __restrict__ Kw,
    const short* __restrict__ Vtg, short* __restrict__ Ow) {
  int l0 = blockIdx.x * 128;
  int h  = blockIdx.y;
  int b  = blockIdx.z;
  __shared__ alignas(16) short Kt[2][64 * LDK];
  __shared__ alignas(16) short Vt[2][64 * LDV];
  int t = threadIdx.x, lane = t & 63, w = t >> 6;
  int l5 = lane & 31, hi = lane >> 5;

  short8 qf[4];
  {
    int qrow = b * L_ + l0 + w * 32 + l5;
    const short* qp = Qw + ((size_t)qrow * H_ + h) * D_ + hi * 8;
#pragma unroll
    for (int kc = 0; kc < 4; ++kc) qf[kc] = *(const short8*)(qp + kc * 16);
  }

  f32x16 acc[2];
#pragma unroll
  for (int dt = 0; dt < 2; ++dt)
#pragma unroll
    for (int r = 0; r < 16; ++r) acc[dt][r] = 0.f;
  float lsum = 0.f;

  const short* Kbase = Kw + (size_t)(b * L_) * C_ + h * D_;
  const short* Vbase = Vtg + (size_t)(b * H_ + h) * D_ * L_;

  int sr = t >> 3, sc = (t & 7) * 8;

  {
    short8 kr[2], vr[2];
#pragma unroll
    for (int p = 0; p < 2; ++p) {
      kr[p] = *(const short8*)(Kbase + (size_t)(p * 32 + sr) * C_ + sc);
      vr[p] = *(const short8*)(Vbase + (size_t)(p * 32 + sr) * L_ + sc);
    }
#pragma unroll
    for (int p = 0; p < 2; ++p) {
      *(short8*)(&Kt[0][(p * 32 + sr) * LDK + sc]) = kr[p];
      *(short8*)(&Vt[0][(p * 32 + sr) * LDV + sc]) = vr[p];
    }
  }

  int cur = 0;
  for (int it = 0; it < 32; ++it) {
    __syncthreads();
    short8 kn[2], vn[2];
    if (it < 31) {
      int lr0 = (it + 1) * 64;
#pragma unroll
      for (int p = 0; p < 2; ++p) {
        kn[p] = *(const short8*)(Kbase + (size_t)(lr0 + p * 32 + sr) * C_ + sc);
        vn[p] = *(const short8*)(Vbase + (size_t)(p * 32 + sr) * L_ + lr0 + sc);
      }
    }
    const short* KT = &Kt[cur][0];
    const short* VT = &Vt[cur][0];

    f32x16 st[2];
#pragma unroll
    for (int T = 0; T < 2; ++T)
#pragma unroll
      for (int r = 0; r < 16; ++r) st[T][r] = 0.f;
    __builtin_amdgcn_s_setprio(1);
#pragma unroll
    for (int T = 0; T < 2; ++T)
#pragma unroll
      for (int kc = 0; kc < 4; ++kc) {
        short8 kf = *(const short8*)(KT + (T * 32 + l5) * LDK + kc * 16 + hi * 8);
        st[T] = __builtin_amdgcn_mfma_f32_32x32x16_bf16(kf, qf[kc], st[T], 0, 0, 0);
      }
    __builtin_amdgcn_s_setprio(0);

    short8 va[2][4];
#pragma unroll
    for (int dt = 0; dt < 2; ++dt)
#pragma unroll
      for (int kc = 0; kc < 4; ++kc)
        va[dt][kc] = *(const short8*)(VT + (dt * 32 + l5) * LDV + kc * 16 + hi * 8);

    short8 pfrag[2][2];
#pragma unroll
    for (int T = 0; T < 2; ++T) {
      float ps[16];
#pragma unroll
      for (int r = 0; r < 16; ++r) {
        float pv = __builtin_amdgcn_exp2f(st[T][r]);
        lsum += pv;
        ps[r] = pv;
      }
      unsigned d0 = cvtpk(ps[0], ps[1]),   d1 = cvtpk(ps[2], ps[3]);
      unsigned d2 = cvtpk(ps[4], ps[5]),   d3 = cvtpk(ps[6], ps[7]);
      pl32swap(d0, d2); pl32swap(d1, d3);
      pfrag[T][0] = mk8(d0, d1, d2, d3);
      unsigned e0 = cvtpk(ps[8], ps[9]),   e1 = cvtpk(ps[10], ps[11]);
      unsigned e2 = cvtpk(ps[12], ps[13]), e3 = cvtpk(ps[14], ps[15]);
      pl32swap(e0, e2); pl32swap(e1, e3);
      pfrag[T][1] = mk8(e0, e1, e2, e3);
    }

    __builtin_amdgcn_s_setprio(1);
#pragma unroll
    for (int dt = 0; dt < 2; ++dt)
#pragma unroll
      for (int T = 0; T < 2; ++T)
#pragma unroll
        for (int kc = 0; kc < 2; ++kc)
          acc[dt] = __builtin_amdgcn_mfma_f32_32x32x16_bf16(va[dt][T * 2 + kc], pfrag[T][kc], acc[dt], 0, 0, 0);
    __builtin_amdgcn_s_setprio(0);

    if (it < 31) {
#pragma unroll
      for (int p = 0; p < 2; ++p) {
        *(short8*)(&Kt[cur ^ 1][(p * 32 + sr) * LDK + sc]) = kn[p];
        *(short8*)(&Vt[cur ^ 1][(p * 32 + sr) * LDV + sc]) = vn[p];
      }
    }
    cur ^= 1;
  }

  __syncthreads();
  lsum += __shfl_xor(lsum, 32, 64);
  float inv = 1.0f / lsum;
  short* ot = (short*)&Kt[0][0] + w * (32 * 72);
#pragma unroll
  for (int dt = 0; dt < 2; ++dt)
#pragma unroll
    for (int rq = 0; rq < 4; ++rq) {
      s4v o;
#pragma unroll
      for (int j = 0; j < 4; ++j) o[j] = f2bf(acc[dt][rq * 4 + j] * inv);
      *(s4v*)(ot + l5 * 72 + dt * 32 + rq * 8 + hi * 4) = o;
    }
  __syncthreads();
#pragma unroll
  for (int p = 0; p < 4; ++p) {
    int rr = p * 8 + (lane >> 3);
    int c8b = (lane & 7) * 8;
    short8 v = *(const short8*)(ot + rr * 72 + c8b);
    int qg = b * L_ + l0 + w * 32 + rr;
    *(short8*)(Ow + ((size_t)qg * H_ + h) * D_ + c8b) = v;
  }
}

// ---------------- Kernel 5: output projection, 64x128 tiles (2 blocks/CU) ------
__global__ __launch_bounds__(256) void k_gemm_out(
    const short* __restrict__ Ow, const short* __restrict__ Wot,
    const float* __restrict__ bo, const short* __restrict__ qn,
    float* __restrict__ out) {
  int m0 = blockIdx.x * 64, n0 = blockIdx.y * 128;
  __shared__ alignas(16) char SMEMRAW[24576];   // As 8K | Bs 16K ; Tt 17.4K
  short* As = (short*)SMEMRAW;
  short* Bs = As + 64 * 64;
  float* Tt = (float*)SMEMRAW;                  // 64 x 68 f32
  int t = threadIdx.x, lane = t & 63, w = t >> 6;
  int wm = w & 1, wn = w >> 1;
  int g0 = w * 8 + (lane >> 3);
  int gc = SW8(lane);

  f32x4 zero4 = {0.f, 0.f, 0.f, 0.f};
  f32x4 acc[2][4];
  for (int i = 0; i < 2; ++i) for (int j = 0; j < 4; ++j) acc[i][j] = zero4;

  for (int k0 = 0; k0 < C_; k0 += 64) {
    __syncthreads();
#pragma unroll
    for (int j = 0; j < 2; ++j) {
      int row = j * 32 + g0;
      gload16(Ow + (size_t)(m0 + row) * C_ + k0 + gc, As + (j * 4 + w) * 512);
    }
#pragma unroll
    for (int i = 0; i < 4; ++i) {
      int row = i * 32 + g0;
      gload16(Wot + (size_t)(n0 + row) * C_ + k0 + gc, Bs + (i * 4 + w) * 512);
    }
    __syncthreads();
#pragma unroll
    for (int kk = 0; kk < 2; ++kk) {
      short8 a[2], bf[4];
#pragma unroll
      for (int i = 0; i < 2; ++i) {
        int row = wm * 32 + i * 16 + (lane & 15);
        a[i] = *(const short8*)(As + row * 64 + (((kk * 4 + (lane >> 4)) ^ (row & 7)) << 3));
      }
#pragma unroll
      for (int i = 0; i < 4; ++i) {
        int row = wn * 64 + i * 16 + (lane & 15);
        bf[i] = *(const short8*)(Bs + row * 64 + (((kk * 4 + (lane >> 4)) ^ (row & 7)) << 3));
      }
#pragma unroll
      for (int i = 0; i < 2; ++i)
#pragma unroll
        for (int j = 0; j < 4; ++j)
          acc[i][j] = __builtin_amdgcn_mfma_f32_16x16x32_bf16(a[i], bf[j], acc[i][j], 0, 0, 0);
    }
  }

  // fold bias + residual
  for (int i = 0; i < 2; ++i)
    for (int j = 0; j < 4; ++j) {
      int colg = n0 + wn * 64 + j * 16 + (lane & 15);
      float bia = bo[colg];
      for (int r = 0; r < 4; ++r) {
        int rowg = m0 + wm * 32 + i * 16 + (lane >> 4) * 4 + r;
        acc[i][j][r] += bia + bf2f(qn[(size_t)rowg * C_ + colg]);
      }
    }

  // 2-pass LDS transpose; float4 stores along L
  int bb = m0 >> 11, lb = m0 & (L_ - 1);
#pragma unroll
  for (int pass = 0; pass < 2; ++pass) {
    __syncthreads();
    if (wn == pass) {
#pragma unroll
      for (int i = 0; i < 2; ++i)
#pragma unroll
        for (int j = 0; j < 4; ++j) {
          int cl = j * 16 + (lane & 15);                 // 0..63
          int ll = wm * 32 + i * 16 + (lane >> 4) * 4;   // 0..60
          float4 v = make_float4(acc[i][j][0], acc[i][j][1], acc[i][j][2], acc[i][j][3]);
          *(float4*)&Tt[cl * 68 + ll] = v;
        }
    }
    __syncthreads();
#pragma unroll
    for (int p = 0; p < 4; ++p) {
      int u = p * 256 + t;
      int c  = u >> 4;             // 0..63
      int l4 = (u & 15) * 4;       // 0..60
      float4 v = *(float4*)&Tt[c * 68 + l4];
      int colg = n0 + pass * 64 + c;
      *(float4*)(out + ((size_t)bb * C_ + colg) * L_ + lb + l4) = v;
    }
  }
}

extern "C" void kernel_launch(void* const* d_in, const int* in_sizes, int n_in,
                              void* d_out, int out_size, void* d_ws, size_t ws_size,
                              hipStream_t stream) {
  const float* query     = (const float*)d_in[0];
  const float* key_value = (const float*)d_in[1];
  const float* pos       = (const float*)d_in[2];
  const float* qg        = (const float*)d_in[3];
  const float* qb        = (const float*)d_in[4];
  const float* kg        = (const float*)d_in[5];
  const float* kb        = (const float*)d_in[6];
  const float* Wq        = (const float*)d_in[7];
  const float* bq        = (const float*)d_in[8];
  const float* Wk        = (const float*)d_in[9];
  const float* bk        = (const float*)d_in[10];
  const float* Wv        = (const float*)d_in[11];
  const float* bv        = (const float*)d_in[12];
  const float* Wo        = (const float*)d_in[13];
  const float* bo        = (const float*)d_in[14];
  float* out = (float*)d_out;

  char* ws = (char*)d_ws;
  const size_t SZ = (size_t)B_ * L_ * C_ * 2;   // 8 MB per bf16 (B,L,C) buffer
  short* qn  = (short*)(ws + 0 * SZ);
  short* kvn = (short*)(ws + 1 * SZ);
  short* Qw  = (short*)(ws + 2 * SZ);
  short* Kw  = (short*)(ws + 3 * SZ);
  short* Vtg = (short*)(ws + 4 * SZ);           // V^T [b][h][d][l] (written by gemm z=2)
  short* Ow  = (short*)(ws + 5 * SZ);
  short* Wt  = (short*)(ws + 6 * SZ);           // 4 x 512x512 bf16 = 2 MB

  k_pre<<<dim3(1536), 256, 0, stream>>>(query, key_value, pos, qg, qb, kg, kb,
                                        Wq, Wk, Wv, Wo, qn, kvn, Wt);
  k_gemm_qkv<<<dim3(8192 / 128, C_ / 128, 3), 256, 0, stream>>>(qn, kvn, Wt, bq, bk, bv, Qw, Kw, Vtg);
  k_attn<<<dim3(L_ / 128, H_, B_), 256, 0, stream>>>(Qw, Kw, Vtg, Ow);
  k_gemm_out<<<dim3(8192 / 64, C_ / 128, 1), 256, 0, stream>>>(Ow, Wt + (size_t)3 * C_ * C_, bo, qn, out);
}